// Round 1
// baseline (1807.708 us; speedup 1.0000x reference)
//
#include <hip/hip_runtime.h>
#include <hip/hip_bf16.h>

// ---------------------------------------------------------------------------
// ResidualAttentionBlock: LN1 -> QKV -> MHA -> out-proj(+x) -> LN2 -> FFN(+x)
// B=4, S=1024, d=1024, H=16, dh=64.
// Strategy:
//   - GEMMs: MFMA bf16, 128x128 tile, BK=32, global_load_lds (m97 structure).
//   - QKV GEMM in split-bf16 (hi+lo) x3 MFMA for fp32-like accuracy (softmax
//     argmax stability requires accurate scores).
//   - Attention: fp32 vector flash, 1 wave per query row, LDS K/V tiles.
//   - Weights pre-cast/transposed to bf16 (N,K) layout each call (tiny).
// Workspace layout (bytes), total ~118 MB:
//   [0,16M)      h_hi|h_lo (bf16)  -> later reused as x2 (fp32)
//   [16M,64M)    qkv fp32
//   [64M+3M...]  o bf16, h2 bf16, u bf16, weight copies
// ---------------------------------------------------------------------------

typedef short bf16x8 __attribute__((ext_vector_type(8)));
typedef float f32x4 __attribute__((ext_vector_type(4)));

__device__ __forceinline__ unsigned short f2bf(float f) {
  unsigned int u = __float_as_uint(f);
  unsigned int r = (u + 0x7fffu + ((u >> 16) & 1u)) >> 16;
  return (unsigned short)r;
}
__device__ __forceinline__ float bf2f(unsigned short h) {
  return __uint_as_float(((unsigned int)h) << 16);
}

__device__ __forceinline__ void gld16(const void* g, void* l) {
  __builtin_amdgcn_global_load_lds(
      (const __attribute__((address_space(1))) unsigned int*)g,
      (__attribute__((address_space(3))) unsigned int*)l, 16, 0, 0);
}

// ---------------- weight prep ----------------

__global__ void cast_split_kernel(const float* __restrict__ in,
                                  unsigned short* __restrict__ hi,
                                  unsigned short* __restrict__ lo, int n) {
  int i = blockIdx.x * blockDim.x + threadIdx.x;
  int stride = gridDim.x * blockDim.x;
  for (; i < n; i += stride) {
    float v = in[i];
    unsigned short h = f2bf(v);
    hi[i] = h;
    lo[i] = f2bf(v - bf2f(h));
  }
}

// in: R x C fp32 row-major -> out: C x R bf16 row-major
__global__ void transpose_cast_kernel(const float* __restrict__ in,
                                      unsigned short* __restrict__ out,
                                      int R, int C) {
  __shared__ float t[32][33];
  int bc = blockIdx.x << 5;  // col base in `in`
  int br = blockIdx.y << 5;  // row base in `in`
  int tx = threadIdx.x, ty = threadIdx.y;
#pragma unroll
  for (int i = ty; i < 32; i += 8)
    t[i][tx] = in[(size_t)(br + i) * C + bc + tx];
  __syncthreads();
#pragma unroll
  for (int i = ty; i < 32; i += 8)
    out[(size_t)(bc + i) * R + br + tx] = f2bf(t[tx][i]);
}

// ---------------- layernorm (d=1024 fixed) ----------------

template <bool SPLIT>
__global__ __launch_bounds__(256) void ln_kernel(
    const float* __restrict__ x, const float* __restrict__ gamma,
    const float* __restrict__ beta, unsigned short* __restrict__ hi,
    unsigned short* __restrict__ lo) {
  int row = blockIdx.x, tid = threadIdx.x;
  float4 v = ((const float4*)x)[(size_t)row * 256 + tid];
  float s = v.x + v.y + v.z + v.w;
  float ss = v.x * v.x + v.y * v.y + v.z * v.z + v.w * v.w;
#pragma unroll
  for (int off = 32; off; off >>= 1) {
    s += __shfl_xor(s, off);
    ss += __shfl_xor(ss, off);
  }
  __shared__ float red[8];
  int wid = tid >> 6, lane = tid & 63;
  if (lane == 0) { red[wid] = s; red[4 + wid] = ss; }
  __syncthreads();
  s = red[0] + red[1] + red[2] + red[3];
  ss = red[4] + red[5] + red[6] + red[7];
  float mean = s * (1.f / 1024.f);
  float var = ss * (1.f / 1024.f) - mean * mean;
  float inv = rsqrtf(var + 1e-5f);
  float4 g = ((const float4*)gamma)[tid];
  float4 bt = ((const float4*)beta)[tid];
  float y[4];
  y[0] = (v.x - mean) * inv * g.x + bt.x;
  y[1] = (v.y - mean) * inv * g.y + bt.y;
  y[2] = (v.z - mean) * inv * g.z + bt.z;
  y[3] = (v.w - mean) * inv * g.w + bt.w;
  size_t o = (size_t)row * 1024 + tid * 4;
#pragma unroll
  for (int j = 0; j < 4; ++j) {
    unsigned short hb = f2bf(y[j]);
    hi[o + j] = hb;
    if (SPLIT) lo[o + j] = f2bf(y[j] - bf2f(hb));
  }
}

// ---------------- GEMM: C[M,N] = A[M,K] * W[N,K]^T (+bias)(+resid)(relu) ----
// bf16 MFMA 16x16x32, tile 128x128, BK=32, 4 waves (2x2 of 64x64).

template <bool SPLIT, bool BIAS, bool RESID, bool RELU, bool OUTBF16>
__global__ __launch_bounds__(256) void gemm_kernel(
    const short* __restrict__ Ah, const short* __restrict__ Al,
    const short* __restrict__ Bh, const short* __restrict__ Bl,
    const float* __restrict__ bias, const float* __restrict__ resid,
    void* __restrict__ outp, int M, int N, int K) {
  __shared__ short As[128 * 32];
  __shared__ short Bs[128 * 32];
  __shared__ short As2[SPLIT ? 128 * 32 : 8];
  __shared__ short Bs2[SPLIT ? 128 * 32 : 8];

  const int tid = threadIdx.x;
  const int lane = tid & 63;
  const int wid = tid >> 6;
  const int wr = (wid >> 1) << 6;
  const int wc = (wid & 1) << 6;
  const int l15 = lane & 15, lh = lane >> 4;
  const int rowBase = blockIdx.y << 7;
  const int colBase = blockIdx.x << 7;

  // staging map: thread t -> row t/4 (within 64-row half), 8-bf16 chunk t%4
  const int sr = tid >> 2;
  const int sc = (tid & 3) << 3;
  const short* Ag = Ah + (size_t)(rowBase + sr) * K + sc;
  const short* Bg = Bh + (size_t)(colBase + sr) * K + sc;
  const short* Ag2 = SPLIT ? Al + (size_t)(rowBase + sr) * K + sc : nullptr;
  const short* Bg2 = SPLIT ? Bl + (size_t)(colBase + sr) * K + sc : nullptr;
  short* Asl = As + sr * 32 + sc;
  short* Bsl = Bs + sr * 32 + sc;
  short* Asl2 = As2 + sr * 32 + sc;
  short* Bsl2 = Bs2 + sr * 32 + sc;

  f32x4 acc[4][4];
#pragma unroll
  for (int m = 0; m < 4; ++m)
#pragma unroll
    for (int n = 0; n < 4; ++n) acc[m][n] = (f32x4){0.f, 0.f, 0.f, 0.f};

  const int kT = K >> 5;
  for (int kt = 0; kt < kT; ++kt) {
    const int k0 = kt << 5;
    __syncthreads();
    gld16(Ag + k0, Asl);
    gld16(Ag + k0 + (size_t)64 * K, Asl + 64 * 32);
    gld16(Bg + k0, Bsl);
    gld16(Bg + k0 + (size_t)64 * K, Bsl + 64 * 32);
    if constexpr (SPLIT) {
      gld16(Ag2 + k0, Asl2);
      gld16(Ag2 + k0 + (size_t)64 * K, Asl2 + 64 * 32);
      gld16(Bg2 + k0, Bsl2);
      gld16(Bg2 + k0 + (size_t)64 * K, Bsl2 + 64 * 32);
    }
    __syncthreads();

    bf16x8 af[4], bfr[4];
#pragma unroll
    for (int m = 0; m < 4; ++m)
      af[m] = *(const bf16x8*)&As[(wr + m * 16 + l15) * 32 + lh * 8];
#pragma unroll
    for (int n = 0; n < 4; ++n)
      bfr[n] = *(const bf16x8*)&Bs[(wc + n * 16 + l15) * 32 + lh * 8];
    if constexpr (SPLIT) {
      bf16x8 af2[4], bfr2[4];
#pragma unroll
      for (int m = 0; m < 4; ++m)
        af2[m] = *(const bf16x8*)&As2[(wr + m * 16 + l15) * 32 + lh * 8];
#pragma unroll
      for (int n = 0; n < 4; ++n)
        bfr2[n] = *(const bf16x8*)&Bs2[(wc + n * 16 + l15) * 32 + lh * 8];
#pragma unroll
      for (int m = 0; m < 4; ++m)
#pragma unroll
        for (int n = 0; n < 4; ++n) {
          acc[m][n] = __builtin_amdgcn_mfma_f32_16x16x32_bf16(af[m], bfr[n], acc[m][n], 0, 0, 0);
          acc[m][n] = __builtin_amdgcn_mfma_f32_16x16x32_bf16(af[m], bfr2[n], acc[m][n], 0, 0, 0);
          acc[m][n] = __builtin_amdgcn_mfma_f32_16x16x32_bf16(af2[m], bfr[n], acc[m][n], 0, 0, 0);
        }
    } else {
#pragma unroll
      for (int m = 0; m < 4; ++m)
#pragma unroll
        for (int n = 0; n < 4; ++n)
          acc[m][n] = __builtin_amdgcn_mfma_f32_16x16x32_bf16(af[m], bfr[n], acc[m][n], 0, 0, 0);
    }
  }

  // epilogue: D[row][col], row=(lane>>4)*4+i, col=lane&15 per 16x16 frag
  const int prow = rowBase + wr + lh * 4;
  const int pcol = colBase + wc + l15;
#pragma unroll
  for (int m = 0; m < 4; ++m) {
#pragma unroll
    for (int n = 0; n < 4; ++n) {
      const int c = pcol + n * 16;
      float badd = 0.f;
      if constexpr (BIAS) badd = bias[c];
#pragma unroll
      for (int i = 0; i < 4; ++i) {
        const int r = prow + m * 16 + i;
        float v = acc[m][n][i] + badd;
        if constexpr (RESID) v += resid[(size_t)r * N + c];
        if constexpr (RELU) v = fmaxf(v, 0.f);
        if constexpr (OUTBF16)
          ((unsigned short*)outp)[(size_t)r * N + c] = f2bf(v);
        else
          ((float*)outp)[(size_t)r * N + c] = v;
      }
    }
  }
}

// ---------------- attention: fp32 vector flash ----------------
// grid (S/4, B*H), block 256 = 4 waves; wave w handles query row q0+w.
// qkv layout: [b,s, 3*1024] with q at +0, k at +1024, v at +2048, head h at h*64.

__global__ __launch_bounds__(256) void attn_kernel(
    const float* __restrict__ qkv, unsigned short* __restrict__ o,
    int B, int S, int H) {
  __shared__ float qs[4][64];
  __shared__ float Ks[64][65];
  __shared__ float Vs[64][65];
  const int tid = threadIdx.x, lane = tid & 63, wid = tid >> 6;
  const int bh = blockIdx.y;
  const int b = bh / H, h = bh % H;
  const int q0 = blockIdx.x * 4;
  const size_t base = (size_t)b * S * 3072;

  {
    int r = tid >> 6, e = tid & 63;
    qs[r][e] = qkv[base + (size_t)(q0 + r) * 3072 + h * 64 + e] * 0.125f;
  }

  float m_run = -INFINITY, r_run = 0.f, o_acc = 0.f;
  const int nT = S >> 6;
  for (int kt = 0; kt < nT; ++kt) {
    __syncthreads();
    {
#pragma unroll
      for (int i = 0; i < 4; ++i) {
        int g = tid + i * 256;          // float4 index 0..1023
        int row = g >> 4, c4 = (g & 15) << 2;
        size_t rb = base + (size_t)(kt * 64 + row) * 3072 + h * 64 + c4;
        float4 kv = *(const float4*)&qkv[rb + 1024];
        Ks[row][c4 + 0] = kv.x; Ks[row][c4 + 1] = kv.y;
        Ks[row][c4 + 2] = kv.z; Ks[row][c4 + 3] = kv.w;
        float4 vv = *(const float4*)&qkv[rb + 2048];
        Vs[row][c4 + 0] = vv.x; Vs[row][c4 + 1] = vv.y;
        Vs[row][c4 + 2] = vv.z; Vs[row][c4 + 3] = vv.w;
      }
    }
    __syncthreads();

    float s = 0.f;
#pragma unroll 16
    for (int e = 0; e < 64; ++e) s += qs[wid][e] * Ks[lane][e];

    float tmax = s;
#pragma unroll
    for (int off = 32; off; off >>= 1) tmax = fmaxf(tmax, __shfl_xor(tmax, off));
    float m_new = fmaxf(m_run, tmax);
    float alpha = __expf(m_run - m_new);
    float p = __expf(s - m_new);
    float lsum = p;
#pragma unroll
    for (int off = 32; off; off >>= 1) lsum += __shfl_xor(lsum, off);
    r_run = r_run * alpha + lsum;
    o_acc *= alpha;
#pragma unroll 16
    for (int l2 = 0; l2 < 64; ++l2) {
      float pv = __shfl(p, l2);
      o_acc += pv * Vs[l2][lane];
    }
    m_run = m_new;
  }
  o[(size_t)(b * S + q0 + wid) * 1024 + h * 64 + lane] = f2bf(o_acc / r_run);
}

// ---------------- launch ----------------

extern "C" void kernel_launch(void* const* d_in, const int* in_sizes, int n_in,
                              void* d_out, int out_size, void* d_ws,
                              size_t ws_size, hipStream_t stream) {
  const float* x = (const float*)d_in[0];
  const float* in_project = (const float*)d_in[1];
  const float* out_project = (const float*)d_in[2];
  const float* ln1_g = (const float*)d_in[3];
  const float* ln1_b = (const float*)d_in[4];
  const float* w_up = (const float*)d_in[5];
  const float* b_up = (const float*)d_in[6];
  const float* w_down = (const float*)d_in[7];
  const float* b_down = (const float*)d_in[8];
  const float* ln2_g = (const float*)d_in[9];
  const float* ln2_b = (const float*)d_in[10];

  const int B = in_sizes[0] / (1024 * 1024);
  const int S = 1024, H = 16;
  const int M = B * S;  // 4096

  char* ws = (char*)d_ws;
  short* h_hi = (short*)(ws + 0);                 // 8MB
  short* h_lo = (short*)(ws + 8388608);           // 8MB
  float* x2 = (float*)(ws + 0);                   // 16MB, reuses h (dead)
  float* qkv = (float*)(ws + 16777216);           // 48MB
  short* o = (short*)(ws + 67108864);             // 8MB
  short* h2 = (short*)(ws + 75497472);            // 8MB
  short* u = (short*)(ws + 83886080);             // 16MB
  short* Wq_hi = (short*)(ws + 100663296);        // 6MB
  short* Wq_lo = (short*)(ws + 106954752);        // 6MB
  short* WoT = (short*)(ws + 113246208);          // 2MB
  short* WupT = (short*)(ws + 115343360);         // 4MB
  short* WdnT = (short*)(ws + 119537664);         // 4MB

  // weight prep
  cast_split_kernel<<<2048, 256, 0, stream>>>(in_project, (unsigned short*)Wq_hi,
                                              (unsigned short*)Wq_lo, 3072 * 1024);
  transpose_cast_kernel<<<dim3(32, 32), dim3(32, 8), 0, stream>>>(
      out_project, (unsigned short*)WoT, 1024, 1024);
  transpose_cast_kernel<<<dim3(64, 32), dim3(32, 8), 0, stream>>>(
      w_up, (unsigned short*)WupT, 1024, 2048);
  transpose_cast_kernel<<<dim3(32, 64), dim3(32, 8), 0, stream>>>(
      w_down, (unsigned short*)WdnT, 2048, 1024);

  // LN1 -> h (split bf16)
  ln_kernel<true><<<M, 256, 0, stream>>>(x, ln1_g, ln1_b, (unsigned short*)h_hi,
                                         (unsigned short*)h_lo);

  // QKV GEMM (split-bf16 x3), fp32 out
  gemm_kernel<true, false, false, false, false>
      <<<dim3(3072 / 128, M / 128), 256, 0, stream>>>(
          h_hi, h_lo, Wq_hi, Wq_lo, nullptr, nullptr, qkv, M, 3072, 1024);

  // attention
  attn_kernel<<<dim3(S / 4, B * H), 256, 0, stream>>>(qkv, (unsigned short*)o,
                                                      B, S, H);

  // out-proj + residual x -> x2 (fp32)
  gemm_kernel<false, false, true, false, false>
      <<<dim3(1024 / 128, M / 128), 256, 0, stream>>>(
          o, nullptr, WoT, nullptr, nullptr, x, x2, M, 1024, 1024);

  // LN2 -> h2 (bf16)
  ln_kernel<false><<<M, 256, 0, stream>>>(x2, ln2_g, ln2_b,
                                          (unsigned short*)h2, nullptr);

  // FFN up: relu(h2 @ w_up^T + b_up) -> u (bf16)
  gemm_kernel<false, true, false, true, true>
      <<<dim3(2048 / 128, M / 128), 256, 0, stream>>>(
          h2, nullptr, WupT, nullptr, b_up, nullptr, u, M, 2048, 1024);

  // FFN down: u @ w_down^T + b_down + x2 -> out (fp32)
  gemm_kernel<false, true, true, false, false>
      <<<dim3(1024 / 128, M / 128), 256, 0, stream>>>(
          u, nullptr, WdnT, nullptr, b_down, x2, d_out, M, 1024, 2048);
}

// Round 2
// 321.696 us; speedup vs baseline: 5.6193x; 5.6193x over previous
//
#include <hip/hip_runtime.h>
#include <hip/hip_bf16.h>

// ---------------------------------------------------------------------------
// ResidualAttentionBlock: LN1 -> QKV -> MHA -> out-proj(+x) -> LN2 -> FFN(+x)
// B=4, S=1024, d=1024, H=16, dh=64.
//   - GEMMs: MFMA bf16, 128x128 tile, BK=32, global_load_lds (m97 structure).
//   - QKV GEMM: split-bf16 (hi+lo) x3 MFMA; epilogue writes Q(x0.125) and K
//     as split bf16 [b,h,s,64] and V transposed bf16 [b,h,dim,key].
//   - Attention: MFMA flash. QK^T split-bf16 (3 MFMA), fp32 online softmax,
//     PV bf16 MFMA. K/V staged via global_load_lds with XOR-swizzled source.
// ---------------------------------------------------------------------------

typedef short bf16x8 __attribute__((ext_vector_type(8)));
typedef float f32x4 __attribute__((ext_vector_type(4)));

__device__ __forceinline__ unsigned short f2bf(float f) {
  unsigned int u = __float_as_uint(f);
  unsigned int r = (u + 0x7fffu + ((u >> 16) & 1u)) >> 16;
  return (unsigned short)r;
}
__device__ __forceinline__ float bf2f(unsigned short h) {
  return __uint_as_float(((unsigned int)h) << 16);
}

__device__ __forceinline__ void gld16(const void* g, void* l) {
  __builtin_amdgcn_global_load_lds(
      (const __attribute__((address_space(1))) unsigned int*)g,
      (__attribute__((address_space(3))) unsigned int*)l, 16, 0, 0);
}

// ---------------- weight prep ----------------

__global__ void cast_split_kernel(const float* __restrict__ in,
                                  unsigned short* __restrict__ hi,
                                  unsigned short* __restrict__ lo, int n) {
  int i = blockIdx.x * blockDim.x + threadIdx.x;
  int stride = gridDim.x * blockDim.x;
  for (; i < n; i += stride) {
    float v = in[i];
    unsigned short h = f2bf(v);
    hi[i] = h;
    lo[i] = f2bf(v - bf2f(h));
  }
}

// in: R x C fp32 row-major -> out: C x R bf16 row-major
__global__ void transpose_cast_kernel(const float* __restrict__ in,
                                      unsigned short* __restrict__ out,
                                      int R, int C) {
  __shared__ float t[32][33];
  int bc = blockIdx.x << 5;
  int br = blockIdx.y << 5;
  int tx = threadIdx.x, ty = threadIdx.y;
#pragma unroll
  for (int i = ty; i < 32; i += 8)
    t[i][tx] = in[(size_t)(br + i) * C + bc + tx];
  __syncthreads();
#pragma unroll
  for (int i = ty; i < 32; i += 8)
    out[(size_t)(bc + i) * R + br + tx] = f2bf(t[tx][i]);
}

// ---------------- layernorm (d=1024 fixed) ----------------

template <bool SPLIT>
__global__ __launch_bounds__(256) void ln_kernel(
    const float* __restrict__ x, const float* __restrict__ gamma,
    const float* __restrict__ beta, unsigned short* __restrict__ hi,
    unsigned short* __restrict__ lo) {
  int row = blockIdx.x, tid = threadIdx.x;
  float4 v = ((const float4*)x)[(size_t)row * 256 + tid];
  float s = v.x + v.y + v.z + v.w;
  float ss = v.x * v.x + v.y * v.y + v.z * v.z + v.w * v.w;
#pragma unroll
  for (int off = 32; off; off >>= 1) {
    s += __shfl_xor(s, off);
    ss += __shfl_xor(ss, off);
  }
  __shared__ float red[8];
  int wid = tid >> 6, lane = tid & 63;
  if (lane == 0) { red[wid] = s; red[4 + wid] = ss; }
  __syncthreads();
  s = red[0] + red[1] + red[2] + red[3];
  ss = red[4] + red[5] + red[6] + red[7];
  float mean = s * (1.f / 1024.f);
  float var = ss * (1.f / 1024.f) - mean * mean;
  float inv = rsqrtf(var + 1e-5f);
  float4 g = ((const float4*)gamma)[tid];
  float4 bt = ((const float4*)beta)[tid];
  float y[4];
  y[0] = (v.x - mean) * inv * g.x + bt.x;
  y[1] = (v.y - mean) * inv * g.y + bt.y;
  y[2] = (v.z - mean) * inv * g.z + bt.z;
  y[3] = (v.w - mean) * inv * g.w + bt.w;
  size_t o = (size_t)row * 1024 + tid * 4;
#pragma unroll
  for (int j = 0; j < 4; ++j) {
    unsigned short hb = f2bf(y[j]);
    hi[o + j] = hb;
    if (SPLIT) lo[o + j] = f2bf(y[j] - bf2f(hb));
  }
}

// ---------------- GEMM: C[M,N] = A[M,K] * W[N,K]^T ----------------
// bf16 MFMA 16x16x32, tile 128x128, BK=32, 4 waves (2x2 of 64x64).

template <bool SPLIT, bool BIAS, bool RESID, bool RELU, bool OUTBF16,
          bool QKVOUT>
__global__ __launch_bounds__(256) void gemm_kernel(
    const short* __restrict__ Ah, const short* __restrict__ Al,
    const short* __restrict__ Bh, const short* __restrict__ Bl,
    const float* __restrict__ bias, const float* __restrict__ resid,
    void* __restrict__ outp, int M, int N, int K,
    unsigned short* __restrict__ qh, unsigned short* __restrict__ ql,
    unsigned short* __restrict__ kh, unsigned short* __restrict__ kl,
    unsigned short* __restrict__ vtp) {
  __shared__ short As[128 * 32];
  __shared__ short Bs[128 * 32];
  __shared__ short As2[SPLIT ? 128 * 32 : 8];
  __shared__ short Bs2[SPLIT ? 128 * 32 : 8];

  const int tid = threadIdx.x;
  const int lane = tid & 63;
  const int wid = tid >> 6;
  const int wr = (wid >> 1) << 6;
  const int wc = (wid & 1) << 6;
  const int l15 = lane & 15, lh = lane >> 4;
  const int rowBase = blockIdx.y << 7;
  const int colBase = blockIdx.x << 7;

  const int sr = tid >> 2;
  const int sc = (tid & 3) << 3;
  const short* Ag = Ah + (size_t)(rowBase + sr) * K + sc;
  const short* Bg = Bh + (size_t)(colBase + sr) * K + sc;
  const short* Ag2 = SPLIT ? Al + (size_t)(rowBase + sr) * K + sc : nullptr;
  const short* Bg2 = SPLIT ? Bl + (size_t)(colBase + sr) * K + sc : nullptr;
  short* Asl = As + sr * 32 + sc;
  short* Bsl = Bs + sr * 32 + sc;
  short* Asl2 = As2 + sr * 32 + sc;
  short* Bsl2 = Bs2 + sr * 32 + sc;

  f32x4 acc[4][4];
#pragma unroll
  for (int m = 0; m < 4; ++m)
#pragma unroll
    for (int n = 0; n < 4; ++n) acc[m][n] = (f32x4){0.f, 0.f, 0.f, 0.f};

  const int kT = K >> 5;
  for (int kt = 0; kt < kT; ++kt) {
    const int k0 = kt << 5;
    __syncthreads();
    gld16(Ag + k0, Asl);
    gld16(Ag + k0 + (size_t)64 * K, Asl + 64 * 32);
    gld16(Bg + k0, Bsl);
    gld16(Bg + k0 + (size_t)64 * K, Bsl + 64 * 32);
    if constexpr (SPLIT) {
      gld16(Ag2 + k0, Asl2);
      gld16(Ag2 + k0 + (size_t)64 * K, Asl2 + 64 * 32);
      gld16(Bg2 + k0, Bsl2);
      gld16(Bg2 + k0 + (size_t)64 * K, Bsl2 + 64 * 32);
    }
    __syncthreads();

    bf16x8 af[4], bfr[4];
#pragma unroll
    for (int m = 0; m < 4; ++m)
      af[m] = *(const bf16x8*)&As[(wr + m * 16 + l15) * 32 + lh * 8];
#pragma unroll
    for (int n = 0; n < 4; ++n)
      bfr[n] = *(const bf16x8*)&Bs[(wc + n * 16 + l15) * 32 + lh * 8];
    if constexpr (SPLIT) {
      bf16x8 af2[4], bfr2[4];
#pragma unroll
      for (int m = 0; m < 4; ++m)
        af2[m] = *(const bf16x8*)&As2[(wr + m * 16 + l15) * 32 + lh * 8];
#pragma unroll
      for (int n = 0; n < 4; ++n)
        bfr2[n] = *(const bf16x8*)&Bs2[(wc + n * 16 + l15) * 32 + lh * 8];
#pragma unroll
      for (int m = 0; m < 4; ++m)
#pragma unroll
        for (int n = 0; n < 4; ++n) {
          acc[m][n] = __builtin_amdgcn_mfma_f32_16x16x32_bf16(af[m], bfr[n], acc[m][n], 0, 0, 0);
          acc[m][n] = __builtin_amdgcn_mfma_f32_16x16x32_bf16(af[m], bfr2[n], acc[m][n], 0, 0, 0);
          acc[m][n] = __builtin_amdgcn_mfma_f32_16x16x32_bf16(af2[m], bfr[n], acc[m][n], 0, 0, 0);
        }
    } else {
#pragma unroll
      for (int m = 0; m < 4; ++m)
#pragma unroll
        for (int n = 0; n < 4; ++n)
          acc[m][n] = __builtin_amdgcn_mfma_f32_16x16x32_bf16(af[m], bfr[n], acc[m][n], 0, 0, 0);
    }
  }

  const int prow = rowBase + wr + lh * 4;
  const int pcol = colBase + wc + l15;
#pragma unroll
  for (int m = 0; m < 4; ++m) {
#pragma unroll
    for (int n = 0; n < 4; ++n) {
      const int c = pcol + n * 16;
      float badd = 0.f;
      if constexpr (BIAS) badd = bias[c];
#pragma unroll
      for (int i = 0; i < 4; ++i) {
        const int r = prow + m * 16 + i;
        float v = acc[m][n][i] + badd;
        if constexpr (QKVOUT) {
          // c in [0,3072): 0=Q(scale 1/8, split), 1=K(split), 2=V(transposed)
          const int part = c >> 10;
          const int cc = c & 1023;
          const int head = cc >> 6, dim = cc & 63;
          const int b = r >> 10, s = r & 1023;
          if (part == 0) {
            float y = v * 0.125f;
            size_t idx = (((size_t)(b * 16 + head)) * 1024 + s) * 64 + dim;
            unsigned short hb = f2bf(y);
            qh[idx] = hb;
            ql[idx] = f2bf(y - bf2f(hb));
          } else if (part == 1) {
            size_t idx = (((size_t)(b * 16 + head)) * 1024 + s) * 64 + dim;
            unsigned short hb = f2bf(v);
            kh[idx] = hb;
            kl[idx] = f2bf(v - bf2f(hb));
          } else {
            size_t idx = (((size_t)(b * 16 + head)) * 64 + dim) * 1024 + s;
            vtp[idx] = f2bf(v);
          }
        } else {
          if constexpr (RESID) v += resid[(size_t)r * N + c];
          if constexpr (RELU) v = fmaxf(v, 0.f);
          if constexpr (OUTBF16)
            ((unsigned short*)outp)[(size_t)r * N + c] = f2bf(v);
          else
            ((float*)outp)[(size_t)r * N + c] = v;
        }
      }
    }
  }
}

// ---------------- attention: MFMA flash ----------------
// grid (S/64, B*H), block 256 = 4 waves; wave w owns q rows [q0+16w, q0+16w+16).
// Q,K: [bh, s, 64] bf16 hi/lo (Q pre-scaled by 0.125). V: [bh, dim, s] bf16.
// K/V LDS tiles XOR-swizzled (16B chunk ^= row&7) via pre-swizzled gld16 src.

__global__ __launch_bounds__(256, 4) void attn_mfma_kernel(
    const short* __restrict__ qhi, const short* __restrict__ qlo,
    const short* __restrict__ khi, const short* __restrict__ klo,
    const short* __restrict__ vt, unsigned short* __restrict__ o,
    int S, int H) {
  __shared__ short Kh[64 * 64];
  __shared__ short Kl[64 * 64];
  __shared__ short Vs[64 * 64];
  __shared__ short Pl[4][16 * 66];

  const int tid = threadIdx.x, lane = tid & 63, wid = tid >> 6;
  const int l15 = lane & 15, lh = lane >> 4;
  const int bh = blockIdx.y;
  const int q0 = blockIdx.x << 6;
  const size_t hb = (size_t)bh * S * 64;

  // Q fragments (A-operand): rows q0+wid*16+l15, k = dim
  const size_t qrow = hb + (size_t)(q0 + wid * 16 + l15) * 64;
  bf16x8 aqh[2], aql[2];
  aqh[0] = *(const bf16x8*)(qhi + qrow + lh * 8);
  aqh[1] = *(const bf16x8*)(qhi + qrow + 32 + lh * 8);
  aql[0] = *(const bf16x8*)(qlo + qrow + lh * 8);
  aql[1] = *(const bf16x8*)(qlo + qrow + 32 + lh * 8);

  float m_run[4], l_run[4];
  f32x4 acc_o[4];
#pragma unroll
  for (int i = 0; i < 4; ++i) { m_run[i] = -INFINITY; l_run[i] = 0.f; }
#pragma unroll
  for (int n = 0; n < 4; ++n) acc_o[n] = (f32x4){0.f, 0.f, 0.f, 0.f};

  // staging linear positions (16B chunks): p, p+256
  const int r0 = tid >> 3, c0 = tid & 7;
  const int p1 = tid + 256;
  const int r1 = p1 >> 3, c1 = p1 & 7;

  const int nT = S >> 6;
  for (int kt = 0; kt < nT; ++kt) {
    __syncthreads();
    {
      const size_t kb = hb + (size_t)kt * 64 * 64;
      gld16(khi + kb + r0 * 64 + ((c0 ^ (r0 & 7)) << 3), (char*)Kh + tid * 16);
      gld16(khi + kb + r1 * 64 + ((c1 ^ (r1 & 7)) << 3), (char*)Kh + p1 * 16);
      gld16(klo + kb + r0 * 64 + ((c0 ^ (r0 & 7)) << 3), (char*)Kl + tid * 16);
      gld16(klo + kb + r1 * 64 + ((c1 ^ (r1 & 7)) << 3), (char*)Kl + p1 * 16);
      const short* vg = vt + hb + (size_t)kt * 64;
      gld16(vg + (size_t)r0 * S + ((c0 ^ (r0 & 7)) << 3), (char*)Vs + tid * 16);
      gld16(vg + (size_t)r1 * S + ((c1 ^ (r1 & 7)) << 3), (char*)Vs + p1 * 16);
    }
    __syncthreads();

    // scores: accs[n] = Q(16 rows) . K^T(keys n*16+l15)
    f32x4 accs[4];
#pragma unroll
    for (int n = 0; n < 4; ++n) accs[n] = (f32x4){0.f, 0.f, 0.f, 0.f};
#pragma unroll
    for (int n = 0; n < 4; ++n) {
      const int row = n * 16 + l15;
      const int sw = row & 7;
      const int ro = row * 64;
      bf16x8 bh0 = *(const bf16x8*)&Kh[ro + ((lh ^ sw) << 3)];
      bf16x8 bh1 = *(const bf16x8*)&Kh[ro + (((4 + lh) ^ sw) << 3)];
      bf16x8 bl0 = *(const bf16x8*)&Kl[ro + ((lh ^ sw) << 3)];
      bf16x8 bl1 = *(const bf16x8*)&Kl[ro + (((4 + lh) ^ sw) << 3)];
      accs[n] = __builtin_amdgcn_mfma_f32_16x16x32_bf16(aqh[0], bh0, accs[n], 0, 0, 0);
      accs[n] = __builtin_amdgcn_mfma_f32_16x16x32_bf16(aqh[1], bh1, accs[n], 0, 0, 0);
      accs[n] = __builtin_amdgcn_mfma_f32_16x16x32_bf16(aqh[0], bl0, accs[n], 0, 0, 0);
      accs[n] = __builtin_amdgcn_mfma_f32_16x16x32_bf16(aqh[1], bl1, accs[n], 0, 0, 0);
      accs[n] = __builtin_amdgcn_mfma_f32_16x16x32_bf16(aql[0], bh0, accs[n], 0, 0, 0);
      accs[n] = __builtin_amdgcn_mfma_f32_16x16x32_bf16(aql[1], bh1, accs[n], 0, 0, 0);
    }

    // online softmax. D-layout: row = lh*4+i, col = l15+16n.
    float mt[4];
#pragma unroll
    for (int i = 0; i < 4; ++i) {
      mt[i] = fmaxf(fmaxf(accs[0][i], accs[1][i]), fmaxf(accs[2][i], accs[3][i]));
#pragma unroll
      for (int off = 1; off < 16; off <<= 1)
        mt[i] = fmaxf(mt[i], __shfl_xor(mt[i], off));
    }
    float alpha[4], lt[4];
#pragma unroll
    for (int i = 0; i < 4; ++i) {
      float mn = fmaxf(m_run[i], mt[i]);
      alpha[i] = __expf(m_run[i] - mn);
      m_run[i] = mn;
      lt[i] = 0.f;
    }
#pragma unroll
    for (int n = 0; n < 4; ++n)
#pragma unroll
      for (int i = 0; i < 4; ++i) {
        float p = __expf(accs[n][i] - m_run[i]);
        accs[n][i] = p;
        lt[i] += p;
      }
#pragma unroll
    for (int i = 0; i < 4; ++i) {
#pragma unroll
      for (int off = 1; off < 16; off <<= 1) lt[i] += __shfl_xor(lt[i], off);
      l_run[i] = l_run[i] * alpha[i] + lt[i];
    }
#pragma unroll
    for (int n = 0; n < 4; ++n)
#pragma unroll
      for (int i = 0; i < 4; ++i) acc_o[n][i] *= alpha[i];

    // P -> LDS (bf16), per-wave region, padded stride 66
    short* pw = Pl[wid];
#pragma unroll
    for (int n = 0; n < 4; ++n)
#pragma unroll
      for (int i = 0; i < 4; ++i)
        pw[(lh * 4 + i) * 66 + n * 16 + l15] = (short)f2bf(accs[n][i]);

    // PV: O += P(16 x 64keys) * V^T(dims n*16+l15, keys)
    bf16x8 pa0 = *(const bf16x8*)&pw[l15 * 66 + lh * 8];
    bf16x8 pa1 = *(const bf16x8*)&pw[l15 * 66 + 32 + lh * 8];
#pragma unroll
    for (int n = 0; n < 4; ++n) {
      const int row = n * 16 + l15;
      const int sw = row & 7;
      const int ro = row * 64;
      bf16x8 bv0 = *(const bf16x8*)&Vs[ro + ((lh ^ sw) << 3)];
      bf16x8 bv1 = *(const bf16x8*)&Vs[ro + (((4 + lh) ^ sw) << 3)];
      acc_o[n] = __builtin_amdgcn_mfma_f32_16x16x32_bf16(pa0, bv0, acc_o[n], 0, 0, 0);
      acc_o[n] = __builtin_amdgcn_mfma_f32_16x16x32_bf16(pa1, bv1, acc_o[n], 0, 0, 0);
    }
  }

  // write O: rows q0+wid*16+lh*4+i, col dim = n*16+l15
  const int b = bh >> 4, h = bh & 15;
#pragma unroll
  for (int n = 0; n < 4; ++n)
#pragma unroll
    for (int i = 0; i < 4; ++i) {
      const int r = q0 + wid * 16 + lh * 4 + i;
      const int dim = n * 16 + l15;
      float v = acc_o[n][i] / l_run[i];
      o[((size_t)(b * S + r)) * 1024 + h * 64 + dim] = f2bf(v);
    }
}

// ---------------- launch ----------------

extern "C" void kernel_launch(void* const* d_in, const int* in_sizes, int n_in,
                              void* d_out, int out_size, void* d_ws,
                              size_t ws_size, hipStream_t stream) {
  const float* x = (const float*)d_in[0];
  const float* in_project = (const float*)d_in[1];
  const float* out_project = (const float*)d_in[2];
  const float* ln1_g = (const float*)d_in[3];
  const float* ln1_b = (const float*)d_in[4];
  const float* w_up = (const float*)d_in[5];
  const float* b_up = (const float*)d_in[6];
  const float* w_down = (const float*)d_in[7];
  const float* b_down = (const float*)d_in[8];
  const float* ln2_g = (const float*)d_in[9];
  const float* ln2_b = (const float*)d_in[10];

  const int B = in_sizes[0] / (1024 * 1024);
  const int S = 1024, H = 16;
  const int M = B * S;  // 4096

  char* ws = (char*)d_ws;
  short* h_hi = (short*)(ws + 0);                 // 8MB
  short* h_lo = (short*)(ws + 8388608);           // 8MB
  float* x2 = (float*)(ws + 0);                   // 16MB, reuses h (dead)
  short* qhi = (short*)(ws + 16777216);           // 8MB
  short* qlo = (short*)(ws + 25165824);           // 8MB
  short* khi = (short*)(ws + 33554432);           // 8MB
  short* klo = (short*)(ws + 41943040);           // 8MB
  short* vt  = (short*)(ws + 50331648);           // 8MB
  short* o = (short*)(ws + 67108864);             // 8MB
  short* h2 = (short*)(ws + 75497472);            // 8MB
  short* u = (short*)(ws + 83886080);             // 16MB
  short* Wq_hi = (short*)(ws + 100663296);        // 6MB
  short* Wq_lo = (short*)(ws + 106954752);        // 6MB
  short* WoT = (short*)(ws + 113246208);          // 2MB
  short* WupT = (short*)(ws + 115343360);         // 4MB
  short* WdnT = (short*)(ws + 119537664);         // 4MB

  cast_split_kernel<<<2048, 256, 0, stream>>>(in_project, (unsigned short*)Wq_hi,
                                              (unsigned short*)Wq_lo, 3072 * 1024);
  transpose_cast_kernel<<<dim3(32, 32), dim3(32, 8), 0, stream>>>(
      out_project, (unsigned short*)WoT, 1024, 1024);
  transpose_cast_kernel<<<dim3(64, 32), dim3(32, 8), 0, stream>>>(
      w_up, (unsigned short*)WupT, 1024, 2048);
  transpose_cast_kernel<<<dim3(32, 64), dim3(32, 8), 0, stream>>>(
      w_down, (unsigned short*)WdnT, 2048, 1024);

  ln_kernel<true><<<M, 256, 0, stream>>>(x, ln1_g, ln1_b, (unsigned short*)h_hi,
                                         (unsigned short*)h_lo);

  // QKV GEMM (split x3), epilogue -> q/k split + v^T
  gemm_kernel<true, false, false, false, false, true>
      <<<dim3(3072 / 128, M / 128), 256, 0, stream>>>(
          h_hi, h_lo, Wq_hi, Wq_lo, nullptr, nullptr, nullptr, M, 3072, 1024,
          (unsigned short*)qhi, (unsigned short*)qlo, (unsigned short*)khi,
          (unsigned short*)klo, (unsigned short*)vt);

  attn_mfma_kernel<<<dim3(S / 64, B * H), 256, 0, stream>>>(
      qhi, qlo, khi, klo, vt, (unsigned short*)o, S, H);

  gemm_kernel<false, false, true, false, false, false>
      <<<dim3(1024 / 128, M / 128), 256, 0, stream>>>(
          o, nullptr, WoT, nullptr, nullptr, x, x2, M, 1024, 1024,
          nullptr, nullptr, nullptr, nullptr, nullptr);

  ln_kernel<false><<<M, 256, 0, stream>>>(x2, ln2_g, ln2_b,
                                          (unsigned short*)h2, nullptr);

  gemm_kernel<false, true, false, true, true, false>
      <<<dim3(2048 / 128, M / 128), 256, 0, stream>>>(
          h2, nullptr, WupT, nullptr, b_up, nullptr, u, M, 2048, 1024,
          nullptr, nullptr, nullptr, nullptr, nullptr);

  gemm_kernel<false, true, true, false, false, false>
      <<<dim3(1024 / 128, M / 128), 256, 0, stream>>>(
          u, nullptr, WdnT, nullptr, b_down, x2, d_out, M, 1024, 2048,
          nullptr, nullptr, nullptr, nullptr, nullptr);
}

// Round 3
// 294.617 us; speedup vs baseline: 6.1358x; 1.0919x over previous
//
#include <hip/hip_runtime.h>
#include <hip/hip_bf16.h>

// ---------------------------------------------------------------------------
// ResidualAttentionBlock: LN1 -> QKV -> MHA -> out-proj(+x) -> LN2 -> FFN(+x)
// B=4, S=1024, d=1024, H=16, dh=64.
//   - GEMMs: MFMA bf16, 128x128 tile, BK=32, global_load_lds, 2-phase LDS dbuf.
//   - QK GEMM (N=2048): split-bf16 (hi+lo) x3 MFMA -> Q(x0.125),K split bf16.
//   - V GEMM (N=1024): plain bf16 -> V transposed [b,h,dim,key].
//   - Attention: MFMA flash, dbuf K/V staging, setprio, defer-max (THR=8).
// ---------------------------------------------------------------------------

typedef short bf16x8 __attribute__((ext_vector_type(8)));
typedef float f32x4 __attribute__((ext_vector_type(4)));

__device__ __forceinline__ unsigned short f2bf(float f) {
  unsigned int u = __float_as_uint(f);
  unsigned int r = (u + 0x7fffu + ((u >> 16) & 1u)) >> 16;
  return (unsigned short)r;
}
__device__ __forceinline__ float bf2f(unsigned short h) {
  return __uint_as_float(((unsigned int)h) << 16);
}

__device__ __forceinline__ void gld16(const void* g, void* l) {
  __builtin_amdgcn_global_load_lds(
      (const __attribute__((address_space(1))) unsigned int*)g,
      (__attribute__((address_space(3))) unsigned int*)l, 16, 0, 0);
}

// ---------------- weight prep ----------------

__global__ void cast_split_kernel(const float* __restrict__ in,
                                  unsigned short* __restrict__ hi,
                                  unsigned short* __restrict__ lo, int n) {
  int i = blockIdx.x * blockDim.x + threadIdx.x;
  int stride = gridDim.x * blockDim.x;
  for (; i < n; i += stride) {
    float v = in[i];
    unsigned short h = f2bf(v);
    hi[i] = h;
    lo[i] = f2bf(v - bf2f(h));
  }
}

// three transposes in one launch (z selects matrix)
__global__ void transpose3_kernel(const float* __restrict__ op,
                                  const float* __restrict__ wu,
                                  const float* __restrict__ wd,
                                  unsigned short* __restrict__ oT,
                                  unsigned short* __restrict__ uT,
                                  unsigned short* __restrict__ dT) {
  const float* in;
  unsigned short* out;
  int R, C;
  if (blockIdx.z == 0) { in = op; out = oT; R = 1024; C = 1024; }
  else if (blockIdx.z == 1) { in = wu; out = uT; R = 1024; C = 2048; }
  else { in = wd; out = dT; R = 2048; C = 1024; }
  int bc = blockIdx.x << 5;
  int br = blockIdx.y << 5;
  if (bc >= C || br >= R) return;
  __shared__ float t[32][33];
  int tx = threadIdx.x, ty = threadIdx.y;
#pragma unroll
  for (int i = ty; i < 32; i += 8)
    t[i][tx] = in[(size_t)(br + i) * C + bc + tx];
  __syncthreads();
#pragma unroll
  for (int i = ty; i < 32; i += 8)
    out[(size_t)(bc + i) * R + br + tx] = f2bf(t[tx][i]);
}

// ---------------- layernorm (d=1024 fixed) ----------------

template <bool SPLIT>
__global__ __launch_bounds__(256) void ln_kernel(
    const float* __restrict__ x, const float* __restrict__ gamma,
    const float* __restrict__ beta, unsigned short* __restrict__ hi,
    unsigned short* __restrict__ lo) {
  int row = blockIdx.x, tid = threadIdx.x;
  float4 v = ((const float4*)x)[(size_t)row * 256 + tid];
  float s = v.x + v.y + v.z + v.w;
  float ss = v.x * v.x + v.y * v.y + v.z * v.z + v.w * v.w;
#pragma unroll
  for (int off = 32; off; off >>= 1) {
    s += __shfl_xor(s, off);
    ss += __shfl_xor(ss, off);
  }
  __shared__ float red[8];
  int wid = tid >> 6, lane = tid & 63;
  if (lane == 0) { red[wid] = s; red[4 + wid] = ss; }
  __syncthreads();
  s = red[0] + red[1] + red[2] + red[3];
  ss = red[4] + red[5] + red[6] + red[7];
  float mean = s * (1.f / 1024.f);
  float var = ss * (1.f / 1024.f) - mean * mean;
  float inv = rsqrtf(var + 1e-5f);
  float4 g = ((const float4*)gamma)[tid];
  float4 bt = ((const float4*)beta)[tid];
  float y[4];
  y[0] = (v.x - mean) * inv * g.x + bt.x;
  y[1] = (v.y - mean) * inv * g.y + bt.y;
  y[2] = (v.z - mean) * inv * g.z + bt.z;
  y[3] = (v.w - mean) * inv * g.w + bt.w;
  size_t o = (size_t)row * 1024 + tid * 4;
#pragma unroll
  for (int j = 0; j < 4; ++j) {
    unsigned short hb = f2bf(y[j]);
    hi[o + j] = hb;
    if (SPLIT) lo[o + j] = f2bf(y[j] - bf2f(hb));
  }
}

// ---------------- GEMM: C[M,N] = A[M,K] * W[N,K]^T ----------------
// bf16 MFMA 16x16x32, tile 128x128, BK=32, 4 waves, 2-phase LDS dbuf.
// OUTMODE: 0 normal, 1 QK-split epilogue (N=2048), 2 V-transpose epilogue.

template <bool SPLIT, bool BIAS, bool RESID, bool RELU, bool OUTBF16,
          int OUTMODE>
__global__ __launch_bounds__(256) void gemm_kernel(
    const short* __restrict__ Ah, const short* __restrict__ Al,
    const short* __restrict__ Bh, const short* __restrict__ Bl,
    const float* __restrict__ bias, const float* __restrict__ resid,
    void* __restrict__ outp, int M, int N, int K,
    unsigned short* __restrict__ qh, unsigned short* __restrict__ ql,
    unsigned short* __restrict__ kh, unsigned short* __restrict__ kl,
    unsigned short* __restrict__ vtp) {
  __shared__ short As[2][128 * 32];
  __shared__ short Bs[2][128 * 32];
  __shared__ short As2[SPLIT ? 2 : 1][SPLIT ? 128 * 32 : 8];
  __shared__ short Bs2[SPLIT ? 2 : 1][SPLIT ? 128 * 32 : 8];

  const int tid = threadIdx.x;
  const int lane = tid & 63;
  const int wid = tid >> 6;
  const int wr = (wid >> 1) << 6;
  const int wc = (wid & 1) << 6;
  const int l15 = lane & 15, lh = lane >> 4;
  const int rowBase = blockIdx.y << 7;
  const int colBase = blockIdx.x << 7;

  const int sr = tid >> 2;
  const int sc = (tid & 3) << 3;
  const int soff = sr * 32 + sc;  // == tid*8 shorts, linear per thread
  const short* Ag = Ah + (size_t)(rowBase + sr) * K + sc;
  const short* Bg = Bh + (size_t)(colBase + sr) * K + sc;
  const short* Ag2 = SPLIT ? Al + (size_t)(rowBase + sr) * K + sc : nullptr;
  const short* Bg2 = SPLIT ? Bl + (size_t)(colBase + sr) * K + sc : nullptr;

  f32x4 acc[4][4];
#pragma unroll
  for (int m = 0; m < 4; ++m)
#pragma unroll
    for (int n = 0; n < 4; ++n) acc[m][n] = (f32x4){0.f, 0.f, 0.f, 0.f};

  const int kT = K >> 5;
  // prologue: stage tile 0 into buf 0
  {
    gld16(Ag, &As[0][soff]);
    gld16(Ag + (size_t)64 * K, &As[0][soff + 64 * 32]);
    gld16(Bg, &Bs[0][soff]);
    gld16(Bg + (size_t)64 * K, &Bs[0][soff + 64 * 32]);
    if constexpr (SPLIT) {
      gld16(Ag2, &As2[0][soff]);
      gld16(Ag2 + (size_t)64 * K, &As2[0][soff + 64 * 32]);
      gld16(Bg2, &Bs2[0][soff]);
      gld16(Bg2 + (size_t)64 * K, &Bs2[0][soff + 64 * 32]);
    }
  }

  for (int kt = 0; kt < kT; ++kt) {
    __syncthreads();  // drains this tile's stage (vmcnt0) + all-waves fence
    const int cb = kt & 1;
    if (kt + 1 < kT) {
      const int nb = cb ^ 1;
      const int k0 = (kt + 1) << 5;
      gld16(Ag + k0, &As[nb][soff]);
      gld16(Ag + k0 + (size_t)64 * K, &As[nb][soff + 64 * 32]);
      gld16(Bg + k0, &Bs[nb][soff]);
      gld16(Bg + k0 + (size_t)64 * K, &Bs[nb][soff + 64 * 32]);
      if constexpr (SPLIT) {
        gld16(Ag2 + k0, &As2[nb][soff]);
        gld16(Ag2 + k0 + (size_t)64 * K, &As2[nb][soff + 64 * 32]);
        gld16(Bg2 + k0, &Bs2[nb][soff]);
        gld16(Bg2 + k0 + (size_t)64 * K, &Bs2[nb][soff + 64 * 32]);
      }
    }

    const short* Asb = As[cb];
    const short* Bsb = Bs[cb];
    bf16x8 af[4], bfr[4];
#pragma unroll
    for (int m = 0; m < 4; ++m)
      af[m] = *(const bf16x8*)&Asb[(wr + m * 16 + l15) * 32 + lh * 8];
#pragma unroll
    for (int n = 0; n < 4; ++n)
      bfr[n] = *(const bf16x8*)&Bsb[(wc + n * 16 + l15) * 32 + lh * 8];
    if constexpr (SPLIT) {
      const short* Asb2 = As2[cb];
      const short* Bsb2 = Bs2[cb];
      bf16x8 af2[4], bfr2[4];
#pragma unroll
      for (int m = 0; m < 4; ++m)
        af2[m] = *(const bf16x8*)&Asb2[(wr + m * 16 + l15) * 32 + lh * 8];
#pragma unroll
      for (int n = 0; n < 4; ++n)
        bfr2[n] = *(const bf16x8*)&Bsb2[(wc + n * 16 + l15) * 32 + lh * 8];
#pragma unroll
      for (int m = 0; m < 4; ++m)
#pragma unroll
        for (int n = 0; n < 4; ++n) {
          acc[m][n] = __builtin_amdgcn_mfma_f32_16x16x32_bf16(af[m], bfr[n], acc[m][n], 0, 0, 0);
          acc[m][n] = __builtin_amdgcn_mfma_f32_16x16x32_bf16(af[m], bfr2[n], acc[m][n], 0, 0, 0);
          acc[m][n] = __builtin_amdgcn_mfma_f32_16x16x32_bf16(af2[m], bfr[n], acc[m][n], 0, 0, 0);
        }
    } else {
#pragma unroll
      for (int m = 0; m < 4; ++m)
#pragma unroll
        for (int n = 0; n < 4; ++n)
          acc[m][n] = __builtin_amdgcn_mfma_f32_16x16x32_bf16(af[m], bfr[n], acc[m][n], 0, 0, 0);
    }
  }

  const int prow = rowBase + wr + lh * 4;
  const int pcol = colBase + wc + l15;
#pragma unroll
  for (int m = 0; m < 4; ++m) {
#pragma unroll
    for (int n = 0; n < 4; ++n) {
      const int c = pcol + n * 16;
      float badd = 0.f;
      if constexpr (BIAS) badd = bias[c];
#pragma unroll
      for (int i = 0; i < 4; ++i) {
        const int r = prow + m * 16 + i;
        float v = acc[m][n][i] + badd;
        if constexpr (OUTMODE == 1) {
          // c in [0,2048): 0=Q(scale 1/8, split), 1=K(split)
          const int part = c >> 10;
          const int cc = c & 1023;
          const int head = cc >> 6, dim = cc & 63;
          const int b = r >> 10, s = r & 1023;
          size_t idx = (((size_t)(b * 16 + head)) * 1024 + s) * 64 + dim;
          if (part == 0) {
            float y = v * 0.125f;
            unsigned short hb = f2bf(y);
            qh[idx] = hb;
            ql[idx] = f2bf(y - bf2f(hb));
          } else {
            unsigned short hb = f2bf(v);
            kh[idx] = hb;
            kl[idx] = f2bf(v - bf2f(hb));
          }
        } else if constexpr (OUTMODE == 2) {
          const int head = c >> 6, dim = c & 63;
          const int b = r >> 10, s = r & 1023;
          vtp[(((size_t)(b * 16 + head)) * 64 + dim) * 1024 + s] = f2bf(v);
        } else {
          if constexpr (RESID) v += resid[(size_t)r * N + c];
          if constexpr (RELU) v = fmaxf(v, 0.f);
          if constexpr (OUTBF16)
            ((unsigned short*)outp)[(size_t)r * N + c] = f2bf(v);
          else
            ((float*)outp)[(size_t)r * N + c] = v;
        }
      }
    }
  }
}

// ---------------- attention: MFMA flash, dbuf staging ----------------
// grid (S/64, B*H), block 256 = 4 waves; wave w owns q rows [q0+16w, q0+16w+16).
// Q,K: [bh, s, 64] bf16 hi/lo (Q pre-scaled 0.125). V: [bh, dim, s] bf16.
// K/V LDS XOR-swizzled (16B chunk ^= row&7) via pre-swizzled gld16 source.

__global__ __launch_bounds__(256, 2) void attn_mfma_kernel(
    const short* __restrict__ qhi, const short* __restrict__ qlo,
    const short* __restrict__ khi, const short* __restrict__ klo,
    const short* __restrict__ vt, unsigned short* __restrict__ o,
    int S, int H) {
  __shared__ short Kh[2][64 * 64];
  __shared__ short Kl[2][64 * 64];
  __shared__ short Vs[2][64 * 64];
  __shared__ short Pl[4][16 * 66];

  const int tid = threadIdx.x, lane = tid & 63, wid = tid >> 6;
  const int l15 = lane & 15, lh = lane >> 4;
  const int bh = blockIdx.y;
  const int q0 = blockIdx.x << 6;
  const size_t hb = (size_t)bh * S * 64;

  const size_t qrow = hb + (size_t)(q0 + wid * 16 + l15) * 64;
  bf16x8 aqh[2], aql[2];
  aqh[0] = *(const bf16x8*)(qhi + qrow + lh * 8);
  aqh[1] = *(const bf16x8*)(qhi + qrow + 32 + lh * 8);
  aql[0] = *(const bf16x8*)(qlo + qrow + lh * 8);
  aql[1] = *(const bf16x8*)(qlo + qrow + 32 + lh * 8);

  float m_run[4], l_run[4];
  f32x4 acc_o[4];
#pragma unroll
  for (int i = 0; i < 4; ++i) { m_run[i] = -INFINITY; l_run[i] = 0.f; }
#pragma unroll
  for (int n = 0; n < 4; ++n) acc_o[n] = (f32x4){0.f, 0.f, 0.f, 0.f};

  // staging linear positions (16B chunks): tid, tid+256
  const int r0 = tid >> 3, c0 = tid & 7;
  const int p1 = tid + 256;
  const int r1 = p1 >> 3, c1 = p1 & 7;
  const int sw0 = ((c0 ^ (r0 & 7)) << 3), sw1 = ((c1 ^ (r1 & 7)) << 3);

  const int nT = S >> 6;
  // prologue: stage tile 0 into buf 0
  {
    const size_t kb = hb;
    gld16(khi + kb + r0 * 64 + sw0, (char*)Kh[0] + tid * 16);
    gld16(khi + kb + r1 * 64 + sw1, (char*)Kh[0] + p1 * 16);
    gld16(klo + kb + r0 * 64 + sw0, (char*)Kl[0] + tid * 16);
    gld16(klo + kb + r1 * 64 + sw1, (char*)Kl[0] + p1 * 16);
    const short* vg = vt + hb;
    gld16(vg + (size_t)r0 * S + sw0, (char*)Vs[0] + tid * 16);
    gld16(vg + (size_t)r1 * S + sw1, (char*)Vs[0] + p1 * 16);
  }

  for (int kt = 0; kt < nT; ++kt) {
    __syncthreads();
    const int cb = kt & 1;
    if (kt + 1 < nT) {
      const int nb = cb ^ 1;
      const size_t kb = hb + (size_t)(kt + 1) * 64 * 64;
      gld16(khi + kb + r0 * 64 + sw0, (char*)Kh[nb] + tid * 16);
      gld16(khi + kb + r1 * 64 + sw1, (char*)Kh[nb] + p1 * 16);
      gld16(klo + kb + r0 * 64 + sw0, (char*)Kl[nb] + tid * 16);
      gld16(klo + kb + r1 * 64 + sw1, (char*)Kl[nb] + p1 * 16);
      const short* vg = vt + hb + (size_t)(kt + 1) * 64;
      gld16(vg + (size_t)r0 * S + sw0, (char*)Vs[nb] + tid * 16);
      gld16(vg + (size_t)r1 * S + sw1, (char*)Vs[nb] + p1 * 16);
    }

    const short* KhB = Kh[cb];
    const short* KlB = Kl[cb];
    const short* VsB = Vs[cb];

    // scores
    f32x4 accs[4];
#pragma unroll
    for (int n = 0; n < 4; ++n) accs[n] = (f32x4){0.f, 0.f, 0.f, 0.f};
    __builtin_amdgcn_s_setprio(1);
#pragma unroll
    for (int n = 0; n < 4; ++n) {
      const int row = n * 16 + l15;
      const int sw = row & 7;
      const int ro = row * 64;
      bf16x8 bh0 = *(const bf16x8*)&KhB[ro + ((lh ^ sw) << 3)];
      bf16x8 bh1 = *(const bf16x8*)&KhB[ro + (((4 + lh) ^ sw) << 3)];
      bf16x8 bl0 = *(const bf16x8*)&KlB[ro + ((lh ^ sw) << 3)];
      bf16x8 bl1 = *(const bf16x8*)&KlB[ro + (((4 + lh) ^ sw) << 3)];
      accs[n] = __builtin_amdgcn_mfma_f32_16x16x32_bf16(aqh[0], bh0, accs[n], 0, 0, 0);
      accs[n] = __builtin_amdgcn_mfma_f32_16x16x32_bf16(aqh[1], bh1, accs[n], 0, 0, 0);
      accs[n] = __builtin_amdgcn_mfma_f32_16x16x32_bf16(aqh[0], bl0, accs[n], 0, 0, 0);
      accs[n] = __builtin_amdgcn_mfma_f32_16x16x32_bf16(aqh[1], bl1, accs[n], 0, 0, 0);
      accs[n] = __builtin_amdgcn_mfma_f32_16x16x32_bf16(aql[0], bh0, accs[n], 0, 0, 0);
      accs[n] = __builtin_amdgcn_mfma_f32_16x16x32_bf16(aql[1], bh1, accs[n], 0, 0, 0);
    }
    __builtin_amdgcn_s_setprio(0);

    // online softmax with defer-max (THR=8)
    float mt[4];
#pragma unroll
    for (int i = 0; i < 4; ++i) {
      mt[i] = fmaxf(fmaxf(accs[0][i], accs[1][i]), fmaxf(accs[2][i], accs[3][i]));
#pragma unroll
      for (int off = 1; off < 16; off <<= 1)
        mt[i] = fmaxf(mt[i], __shfl_xor(mt[i], off));
    }
    bool grow = (mt[0] > m_run[0] + 8.f) || (mt[1] > m_run[1] + 8.f) ||
                (mt[2] > m_run[2] + 8.f) || (mt[3] > m_run[3] + 8.f);
    if (__any(grow)) {
#pragma unroll
      for (int i = 0; i < 4; ++i) {
        float mn = fmaxf(m_run[i], mt[i]);
        float a = __expf(m_run[i] - mn);
        m_run[i] = mn;
        l_run[i] *= a;
#pragma unroll
        for (int n = 0; n < 4; ++n) acc_o[n][i] *= a;
      }
    }
    float lt[4] = {0.f, 0.f, 0.f, 0.f};
#pragma unroll
    for (int n = 0; n < 4; ++n)
#pragma unroll
      for (int i = 0; i < 4; ++i) {
        float p = __expf(accs[n][i] - m_run[i]);
        accs[n][i] = p;
        lt[i] += p;
      }
#pragma unroll
    for (int i = 0; i < 4; ++i) {
#pragma unroll
      for (int off = 1; off < 16; off <<= 1) lt[i] += __shfl_xor(lt[i], off);
      l_run[i] += lt[i];
    }

    // P -> LDS (bf16), per-wave region, padded stride 66
    short* pw = Pl[wid];
#pragma unroll
    for (int n = 0; n < 4; ++n)
#pragma unroll
      for (int i = 0; i < 4; ++i)
        pw[(lh * 4 + i) * 66 + n * 16 + l15] = (short)f2bf(accs[n][i]);

    bf16x8 pa0 = *(const bf16x8*)&pw[l15 * 66 + lh * 8];
    bf16x8 pa1 = *(const bf16x8*)&pw[l15 * 66 + 32 + lh * 8];
    __builtin_amdgcn_s_setprio(1);
#pragma unroll
    for (int n = 0; n < 4; ++n) {
      const int row = n * 16 + l15;
      const int sw = row & 7;
      const int ro = row * 64;
      bf16x8 bv0 = *(const bf16x8*)&VsB[ro + ((lh ^ sw) << 3)];
      bf16x8 bv1 = *(const bf16x8*)&VsB[ro + (((4 + lh) ^ sw) << 3)];
      acc_o[n] = __builtin_amdgcn_mfma_f32_16x16x32_bf16(pa0, bv0, acc_o[n], 0, 0, 0);
      acc_o[n] = __builtin_amdgcn_mfma_f32_16x16x32_bf16(pa1, bv1, acc_o[n], 0, 0, 0);
    }
    __builtin_amdgcn_s_setprio(0);
  }

  const int b = bh >> 4, h = bh & 15;
#pragma unroll
  for (int n = 0; n < 4; ++n)
#pragma unroll
    for (int i = 0; i < 4; ++i) {
      const int r = q0 + wid * 16 + lh * 4 + i;
      const int dim = n * 16 + l15;
      float v = acc_o[n][i] / l_run[i];
      o[((size_t)(b * S + r)) * 1024 + h * 64 + dim] = f2bf(v);
    }
}

// ---------------- launch ----------------

extern "C" void kernel_launch(void* const* d_in, const int* in_sizes, int n_in,
                              void* d_out, int out_size, void* d_ws,
                              size_t ws_size, hipStream_t stream) {
  const float* x = (const float*)d_in[0];
  const float* in_project = (const float*)d_in[1];
  const float* out_project = (const float*)d_in[2];
  const float* ln1_g = (const float*)d_in[3];
  const float* ln1_b = (const float*)d_in[4];
  const float* w_up = (const float*)d_in[5];
  const float* b_up = (const float*)d_in[6];
  const float* w_down = (const float*)d_in[7];
  const float* b_down = (const float*)d_in[8];
  const float* ln2_g = (const float*)d_in[9];
  const float* ln2_b = (const float*)d_in[10];

  const int B = in_sizes[0] / (1024 * 1024);
  const int S = 1024, H = 16;
  const int M = B * S;  // 4096

  char* ws = (char*)d_ws;
  short* h_hi = (short*)(ws + 0);                 // 8MB
  short* h_lo = (short*)(ws + 8388608);           // 8MB
  float* x2 = (float*)(ws + 0);                   // 16MB, reuses h (dead)
  short* qhi = (short*)(ws + 16777216);           // 8MB
  short* qlo = (short*)(ws + 25165824);           // 8MB
  short* khi = (short*)(ws + 33554432);           // 8MB
  short* klo = (short*)(ws + 41943040);           // 8MB
  short* vt  = (short*)(ws + 50331648);           // 8MB
  short* o = (short*)(ws + 67108864);             // 8MB
  short* h2 = (short*)(ws + 75497472);            // 8MB
  short* u = (short*)(ws + 83886080);             // 16MB
  short* Wq_hi = (short*)(ws + 100663296);        // 6MB
  short* Wq_lo = (short*)(ws + 106954752);        // 6MB
  short* WoT = (short*)(ws + 113246208);          // 2MB
  short* WupT = (short*)(ws + 115343360);         // 4MB
  short* WdnT = (short*)(ws + 119537664);         // 4MB

  cast_split_kernel<<<2048, 256, 0, stream>>>(in_project, (unsigned short*)Wq_hi,
                                              (unsigned short*)Wq_lo, 3072 * 1024);
  transpose3_kernel<<<dim3(64, 64, 3), dim3(32, 8), 0, stream>>>(
      out_project, w_up, w_down, (unsigned short*)WoT, (unsigned short*)WupT,
      (unsigned short*)WdnT);

  ln_kernel<true><<<M, 256, 0, stream>>>(x, ln1_g, ln1_b, (unsigned short*)h_hi,
                                         (unsigned short*)h_lo);

  // QK GEMM (split x3, N=2048) -> q/k split bf16
  gemm_kernel<true, false, false, false, false, 1>
      <<<dim3(2048 / 128, M / 128), 256, 0, stream>>>(
          h_hi, h_lo, Wq_hi, Wq_lo, nullptr, nullptr, nullptr, M, 2048, 1024,
          (unsigned short*)qhi, (unsigned short*)qlo, (unsigned short*)khi,
          (unsigned short*)klo, nullptr);

  // V GEMM (plain, N=1024) -> v^T bf16
  gemm_kernel<false, false, false, false, false, 2>
      <<<dim3(1024 / 128, M / 128), 256, 0, stream>>>(
          h_hi, nullptr, Wq_hi + (size_t)2048 * 1024, nullptr, nullptr, nullptr,
          nullptr, M, 1024, 1024, nullptr, nullptr, nullptr, nullptr,
          (unsigned short*)vt);

  attn_mfma_kernel<<<dim3(S / 64, B * H), 256, 0, stream>>>(
      qhi, qlo, khi, klo, vt, (unsigned short*)o, S, H);

  gemm_kernel<false, false, true, false, false, 0>
      <<<dim3(1024 / 128, M / 128), 256, 0, stream>>>(
          o, nullptr, WoT, nullptr, nullptr, x, x2, M, 1024, 1024,
          nullptr, nullptr, nullptr, nullptr, nullptr);

  ln_kernel<false><<<M, 256, 0, stream>>>(x2, ln2_g, ln2_b,
                                          (unsigned short*)h2, nullptr);

  gemm_kernel<false, true, false, true, true, 0>
      <<<dim3(2048 / 128, M / 128), 256, 0, stream>>>(
          h2, nullptr, WupT, nullptr, b_up, nullptr, u, M, 2048, 1024,
          nullptr, nullptr, nullptr, nullptr, nullptr);

  gemm_kernel<false, true, true, false, false, 0>
      <<<dim3(1024 / 128, M / 128), 256, 0, stream>>>(
          u, nullptr, WdnT, nullptr, b_down, x2, d_out, M, 1024, 2048,
          nullptr, nullptr, nullptr, nullptr, nullptr);
}

// Round 4
// 275.118 us; speedup vs baseline: 6.5707x; 1.0709x over previous
//
#include <hip/hip_runtime.h>
#include <hip/hip_bf16.h>

// ---------------------------------------------------------------------------
// ResidualAttentionBlock: LN1 -> QKV -> MHA -> out-proj(+x) -> LN2 -> FFN(+x)
// B=4, S=1024, d=1024, H=16, dh=64.
//   - GEMMs: MFMA bf16, 128x128 tile, BK=32, global_load_lds, 2-phase LDS dbuf.
//   - QK GEMM (N=2048): split-bf16 (hi+lo) x3 MFMA -> Q(x0.125),K split bf16.
//   - V GEMM (N=1024): plain bf16 -> V transposed [b,h,dim,key].
//   - Attention: MFMA flash, QBLK=128 (8 waves), XCD-aware grid so each XCD's
//     L2 holds 8 heads' K/V (3MB < 4MB) -> kills HBM re-fetch (was 106MB).
// ---------------------------------------------------------------------------

typedef short bf16x8 __attribute__((ext_vector_type(8)));
typedef float f32x4 __attribute__((ext_vector_type(4)));

__device__ __forceinline__ unsigned short f2bf(float f) {
  unsigned int u = __float_as_uint(f);
  unsigned int r = (u + 0x7fffu + ((u >> 16) & 1u)) >> 16;
  return (unsigned short)r;
}
__device__ __forceinline__ float bf2f(unsigned short h) {
  return __uint_as_float(((unsigned int)h) << 16);
}

__device__ __forceinline__ void gld16(const void* g, void* l) {
  __builtin_amdgcn_global_load_lds(
      (const __attribute__((address_space(1))) unsigned int*)g,
      (__attribute__((address_space(3))) unsigned int*)l, 16, 0, 0);
}

// ---------------- weight prep ----------------

__global__ void cast_split_kernel(const float* __restrict__ in,
                                  unsigned short* __restrict__ hi,
                                  unsigned short* __restrict__ lo, int n) {
  int i = blockIdx.x * blockDim.x + threadIdx.x;
  int stride = gridDim.x * blockDim.x;
  for (; i < n; i += stride) {
    float v = in[i];
    unsigned short h = f2bf(v);
    hi[i] = h;
    lo[i] = f2bf(v - bf2f(h));
  }
}

// three transposes in one launch (z selects matrix)
__global__ void transpose3_kernel(const float* __restrict__ op,
                                  const float* __restrict__ wu,
                                  const float* __restrict__ wd,
                                  unsigned short* __restrict__ oT,
                                  unsigned short* __restrict__ uT,
                                  unsigned short* __restrict__ dT) {
  const float* in;
  unsigned short* out;
  int R, C;
  if (blockIdx.z == 0) { in = op; out = oT; R = 1024; C = 1024; }
  else if (blockIdx.z == 1) { in = wu; out = uT; R = 1024; C = 2048; }
  else { in = wd; out = dT; R = 2048; C = 1024; }
  int bc = blockIdx.x << 5;
  int br = blockIdx.y << 5;
  if (bc >= C || br >= R) return;
  __shared__ float t[32][33];
  int tx = threadIdx.x, ty = threadIdx.y;
#pragma unroll
  for (int i = ty; i < 32; i += 8)
    t[i][tx] = in[(size_t)(br + i) * C + bc + tx];
  __syncthreads();
#pragma unroll
  for (int i = ty; i < 32; i += 8)
    out[(size_t)(bc + i) * R + br + tx] = f2bf(t[tx][i]);
}

// ---------------- layernorm (d=1024 fixed) ----------------

template <bool SPLIT>
__global__ __launch_bounds__(256) void ln_kernel(
    const float* __restrict__ x, const float* __restrict__ gamma,
    const float* __restrict__ beta, unsigned short* __restrict__ hi,
    unsigned short* __restrict__ lo) {
  int row = blockIdx.x, tid = threadIdx.x;
  float4 v = ((const float4*)x)[(size_t)row * 256 + tid];
  float s = v.x + v.y + v.z + v.w;
  float ss = v.x * v.x + v.y * v.y + v.z * v.z + v.w * v.w;
#pragma unroll
  for (int off = 32; off; off >>= 1) {
    s += __shfl_xor(s, off);
    ss += __shfl_xor(ss, off);
  }
  __shared__ float red[8];
  int wid = tid >> 6, lane = tid & 63;
  if (lane == 0) { red[wid] = s; red[4 + wid] = ss; }
  __syncthreads();
  s = red[0] + red[1] + red[2] + red[3];
  ss = red[4] + red[5] + red[6] + red[7];
  float mean = s * (1.f / 1024.f);
  float var = ss * (1.f / 1024.f) - mean * mean;
  float inv = rsqrtf(var + 1e-5f);
  float4 g = ((const float4*)gamma)[tid];
  float4 bt = ((const float4*)beta)[tid];
  float y[4];
  y[0] = (v.x - mean) * inv * g.x + bt.x;
  y[1] = (v.y - mean) * inv * g.y + bt.y;
  y[2] = (v.z - mean) * inv * g.z + bt.z;
  y[3] = (v.w - mean) * inv * g.w + bt.w;
  size_t o = (size_t)row * 1024 + tid * 4;
#pragma unroll
  for (int j = 0; j < 4; ++j) {
    unsigned short hb = f2bf(y[j]);
    hi[o + j] = hb;
    if (SPLIT) lo[o + j] = f2bf(y[j] - bf2f(hb));
  }
}

// ---------------- GEMM: C[M,N] = A[M,K] * W[N,K]^T ----------------
// bf16 MFMA 16x16x32, tile 128x128, BK=32, 4 waves, 2-phase LDS dbuf.
// OUTMODE: 0 normal, 1 QK-split epilogue (N=2048), 2 V-transpose epilogue.

template <bool SPLIT, bool BIAS, bool RESID, bool RELU, bool OUTBF16,
          int OUTMODE>
__global__ __launch_bounds__(256) void gemm_kernel(
    const short* __restrict__ Ah, const short* __restrict__ Al,
    const short* __restrict__ Bh, const short* __restrict__ Bl,
    const float* __restrict__ bias, const float* __restrict__ resid,
    void* __restrict__ outp, int M, int N, int K,
    unsigned short* __restrict__ qh, unsigned short* __restrict__ ql,
    unsigned short* __restrict__ kh, unsigned short* __restrict__ kl,
    unsigned short* __restrict__ vtp) {
  __shared__ short As[2][128 * 32];
  __shared__ short Bs[2][128 * 32];
  __shared__ short As2[SPLIT ? 2 : 1][SPLIT ? 128 * 32 : 8];
  __shared__ short Bs2[SPLIT ? 2 : 1][SPLIT ? 128 * 32 : 8];

  const int tid = threadIdx.x;
  const int lane = tid & 63;
  const int wid = tid >> 6;
  const int wr = (wid >> 1) << 6;
  const int wc = (wid & 1) << 6;
  const int l15 = lane & 15, lh = lane >> 4;
  const int rowBase = blockIdx.y << 7;
  const int colBase = blockIdx.x << 7;

  const int sr = tid >> 2;
  const int sc = (tid & 3) << 3;
  const int soff = sr * 32 + sc;
  const short* Ag = Ah + (size_t)(rowBase + sr) * K + sc;
  const short* Bg = Bh + (size_t)(colBase + sr) * K + sc;
  const short* Ag2 = SPLIT ? Al + (size_t)(rowBase + sr) * K + sc : nullptr;
  const short* Bg2 = SPLIT ? Bl + (size_t)(colBase + sr) * K + sc : nullptr;

  f32x4 acc[4][4];
#pragma unroll
  for (int m = 0; m < 4; ++m)
#pragma unroll
    for (int n = 0; n < 4; ++n) acc[m][n] = (f32x4){0.f, 0.f, 0.f, 0.f};

  const int kT = K >> 5;
  {
    gld16(Ag, &As[0][soff]);
    gld16(Ag + (size_t)64 * K, &As[0][soff + 64 * 32]);
    gld16(Bg, &Bs[0][soff]);
    gld16(Bg + (size_t)64 * K, &Bs[0][soff + 64 * 32]);
    if constexpr (SPLIT) {
      gld16(Ag2, &As2[0][soff]);
      gld16(Ag2 + (size_t)64 * K, &As2[0][soff + 64 * 32]);
      gld16(Bg2, &Bs2[0][soff]);
      gld16(Bg2 + (size_t)64 * K, &Bs2[0][soff + 64 * 32]);
    }
  }

  for (int kt = 0; kt < kT; ++kt) {
    __syncthreads();
    const int cb = kt & 1;
    if (kt + 1 < kT) {
      const int nb = cb ^ 1;
      const int k0 = (kt + 1) << 5;
      gld16(Ag + k0, &As[nb][soff]);
      gld16(Ag + k0 + (size_t)64 * K, &As[nb][soff + 64 * 32]);
      gld16(Bg + k0, &Bs[nb][soff]);
      gld16(Bg + k0 + (size_t)64 * K, &Bs[nb][soff + 64 * 32]);
      if constexpr (SPLIT) {
        gld16(Ag2 + k0, &As2[nb][soff]);
        gld16(Ag2 + k0 + (size_t)64 * K, &As2[nb][soff + 64 * 32]);
        gld16(Bg2 + k0, &Bs2[nb][soff]);
        gld16(Bg2 + k0 + (size_t)64 * K, &Bs2[nb][soff + 64 * 32]);
      }
    }

    const short* Asb = As[cb];
    const short* Bsb = Bs[cb];
    bf16x8 af[4], bfr[4];
#pragma unroll
    for (int m = 0; m < 4; ++m)
      af[m] = *(const bf16x8*)&Asb[(wr + m * 16 + l15) * 32 + lh * 8];
#pragma unroll
    for (int n = 0; n < 4; ++n)
      bfr[n] = *(const bf16x8*)&Bsb[(wc + n * 16 + l15) * 32 + lh * 8];
    if constexpr (SPLIT) {
      const short* Asb2 = As2[cb];
      const short* Bsb2 = Bs2[cb];
      bf16x8 af2[4], bfr2[4];
#pragma unroll
      for (int m = 0; m < 4; ++m)
        af2[m] = *(const bf16x8*)&Asb2[(wr + m * 16 + l15) * 32 + lh * 8];
#pragma unroll
      for (int n = 0; n < 4; ++n)
        bfr2[n] = *(const bf16x8*)&Bsb2[(wc + n * 16 + l15) * 32 + lh * 8];
#pragma unroll
      for (int m = 0; m < 4; ++m)
#pragma unroll
        for (int n = 0; n < 4; ++n) {
          acc[m][n] = __builtin_amdgcn_mfma_f32_16x16x32_bf16(af[m], bfr[n], acc[m][n], 0, 0, 0);
          acc[m][n] = __builtin_amdgcn_mfma_f32_16x16x32_bf16(af[m], bfr2[n], acc[m][n], 0, 0, 0);
          acc[m][n] = __builtin_amdgcn_mfma_f32_16x16x32_bf16(af2[m], bfr[n], acc[m][n], 0, 0, 0);
        }
    } else {
#pragma unroll
      for (int m = 0; m < 4; ++m)
#pragma unroll
        for (int n = 0; n < 4; ++n)
          acc[m][n] = __builtin_amdgcn_mfma_f32_16x16x32_bf16(af[m], bfr[n], acc[m][n], 0, 0, 0);
    }
  }

  const int prow = rowBase + wr + lh * 4;
  const int pcol = colBase + wc + l15;
#pragma unroll
  for (int m = 0; m < 4; ++m) {
#pragma unroll
    for (int n = 0; n < 4; ++n) {
      const int c = pcol + n * 16;
      float badd = 0.f;
      if constexpr (BIAS) badd = bias[c];
#pragma unroll
      for (int i = 0; i < 4; ++i) {
        const int r = prow + m * 16 + i;
        float v = acc[m][n][i] + badd;
        if constexpr (OUTMODE == 1) {
          const int part = c >> 10;
          const int cc = c & 1023;
          const int head = cc >> 6, dim = cc & 63;
          const int b = r >> 10, s = r & 1023;
          size_t idx = (((size_t)(b * 16 + head)) * 1024 + s) * 64 + dim;
          if (part == 0) {
            float y = v * 0.125f;
            unsigned short hb = f2bf(y);
            qh[idx] = hb;
            ql[idx] = f2bf(y - bf2f(hb));
          } else {
            unsigned short hb = f2bf(v);
            kh[idx] = hb;
            kl[idx] = f2bf(v - bf2f(hb));
          }
        } else if constexpr (OUTMODE == 2) {
          const int head = c >> 6, dim = c & 63;
          const int b = r >> 10, s = r & 1023;
          vtp[(((size_t)(b * 16 + head)) * 64 + dim) * 1024 + s] = f2bf(v);
        } else {
          if constexpr (RESID) v += resid[(size_t)r * N + c];
          if constexpr (RELU) v = fmaxf(v, 0.f);
          if constexpr (OUTBF16)
            ((unsigned short*)outp)[(size_t)r * N + c] = f2bf(v);
          else
            ((float*)outp)[(size_t)r * N + c] = v;
        }
      }
    }
  }
}

// ---------------- attention: MFMA flash, QBLK=128, XCD-aware grid ----------
// 1D grid of 512 blocks, 512 threads (8 waves x 16 q-rows).
// Mapping: xcd = blk&7 gets heads [xcd*8, xcd*8+8) for all 8 q-tiles ->
// per-XCD K/V footprint 3MB fits the 4MB L2 (kills HBM re-fetch).
// Q,K: [bh, s, 64] bf16 hi/lo (Q pre-scaled 0.125). V: [bh, dim, s] bf16.
// K/V LDS XOR-swizzled (16B chunk ^= row&7) via pre-swizzled gld16 source.

__global__ __launch_bounds__(512, 2) void attn_mfma_kernel(
    const short* __restrict__ qhi, const short* __restrict__ qlo,
    const short* __restrict__ khi, const short* __restrict__ klo,
    const short* __restrict__ vt, unsigned short* __restrict__ o,
    int S, int H) {
  __shared__ short Kh[2][64 * 64];
  __shared__ short Kl[2][64 * 64];
  __shared__ short Vs[2][64 * 64];
  __shared__ short Pl[8][16 * 66];

  const int tid = threadIdx.x, lane = tid & 63, wid = tid >> 6;
  const int l15 = lane & 15, lh = lane >> 4;
  // XCD-aware decode: blk&7 = xcd slot; each xcd owns 8 consecutive heads.
  const int blk = blockIdx.x;
  const int j = blk >> 3;
  const int bh = ((blk & 7) << 3) + (j & 7);
  const int q0 = (j >> 3) << 7;
  const size_t hb = (size_t)bh * S * 64;

  const size_t qrow = hb + (size_t)(q0 + wid * 16 + l15) * 64;
  bf16x8 aqh[2], aql[2];
  aqh[0] = *(const bf16x8*)(qhi + qrow + lh * 8);
  aqh[1] = *(const bf16x8*)(qhi + qrow + 32 + lh * 8);
  aql[0] = *(const bf16x8*)(qlo + qrow + lh * 8);
  aql[1] = *(const bf16x8*)(qlo + qrow + 32 + lh * 8);

  float m_run[4], l_run[4];
  f32x4 acc_o[4];
#pragma unroll
  for (int i = 0; i < 4; ++i) { m_run[i] = -INFINITY; l_run[i] = 0.f; }
#pragma unroll
  for (int n = 0; n < 4; ++n) acc_o[n] = (f32x4){0.f, 0.f, 0.f, 0.f};

  // staging: 512 threads cover 512 16B-chunks (one per thread per array)
  const int r0 = tid >> 3, c0 = tid & 7;
  const int sw0 = ((c0 ^ (r0 & 7)) << 3);

  const int nT = S >> 6;
  {
    gld16(khi + hb + r0 * 64 + sw0, (char*)Kh[0] + tid * 16);
    gld16(klo + hb + r0 * 64 + sw0, (char*)Kl[0] + tid * 16);
    gld16(vt + hb + (size_t)r0 * S + sw0, (char*)Vs[0] + tid * 16);
  }

  for (int kt = 0; kt < nT; ++kt) {
    __syncthreads();
    const int cb = kt & 1;
    if (kt + 1 < nT) {
      const int nb = cb ^ 1;
      const size_t kb = hb + (size_t)(kt + 1) * 64 * 64;
      gld16(khi + kb + r0 * 64 + sw0, (char*)Kh[nb] + tid * 16);
      gld16(klo + kb + r0 * 64 + sw0, (char*)Kl[nb] + tid * 16);
      const short* vg = vt + hb + (size_t)(kt + 1) * 64;
      gld16(vg + (size_t)r0 * S + sw0, (char*)Vs[nb] + tid * 16);
    }

    const short* KhB = Kh[cb];
    const short* KlB = Kl[cb];
    const short* VsB = Vs[cb];

    f32x4 accs[4];
#pragma unroll
    for (int n = 0; n < 4; ++n) accs[n] = (f32x4){0.f, 0.f, 0.f, 0.f};
    __builtin_amdgcn_s_setprio(1);
#pragma unroll
    for (int n = 0; n < 4; ++n) {
      const int row = n * 16 + l15;
      const int sw = row & 7;
      const int ro = row * 64;
      bf16x8 bh0 = *(const bf16x8*)&KhB[ro + ((lh ^ sw) << 3)];
      bf16x8 bh1 = *(const bf16x8*)&KhB[ro + (((4 + lh) ^ sw) << 3)];
      bf16x8 bl0 = *(const bf16x8*)&KlB[ro + ((lh ^ sw) << 3)];
      bf16x8 bl1 = *(const bf16x8*)&KlB[ro + (((4 + lh) ^ sw) << 3)];
      accs[n] = __builtin_amdgcn_mfma_f32_16x16x32_bf16(aqh[0], bh0, accs[n], 0, 0, 0);
      accs[n] = __builtin_amdgcn_mfma_f32_16x16x32_bf16(aqh[1], bh1, accs[n], 0, 0, 0);
      accs[n] = __builtin_amdgcn_mfma_f32_16x16x32_bf16(aqh[0], bl0, accs[n], 0, 0, 0);
      accs[n] = __builtin_amdgcn_mfma_f32_16x16x32_bf16(aqh[1], bl1, accs[n], 0, 0, 0);
      accs[n] = __builtin_amdgcn_mfma_f32_16x16x32_bf16(aql[0], bh0, accs[n], 0, 0, 0);
      accs[n] = __builtin_amdgcn_mfma_f32_16x16x32_bf16(aql[1], bh1, accs[n], 0, 0, 0);
    }
    __builtin_amdgcn_s_setprio(0);

    // online softmax with defer-max (THR=8)
    float mt[4];
#pragma unroll
    for (int i = 0; i < 4; ++i) {
      mt[i] = fmaxf(fmaxf(accs[0][i], accs[1][i]), fmaxf(accs[2][i], accs[3][i]));
#pragma unroll
      for (int off = 1; off < 16; off <<= 1)
        mt[i] = fmaxf(mt[i], __shfl_xor(mt[i], off));
    }
    bool grow = (mt[0] > m_run[0] + 8.f) || (mt[1] > m_run[1] + 8.f) ||
                (mt[2] > m_run[2] + 8.f) || (mt[3] > m_run[3] + 8.f);
    if (__any(grow)) {
#pragma unroll
      for (int i = 0; i < 4; ++i) {
        float mn = fmaxf(m_run[i], mt[i]);
        float a = __expf(m_run[i] - mn);
        m_run[i] = mn;
        l_run[i] *= a;
#pragma unroll
        for (int n = 0; n < 4; ++n) acc_o[n][i] *= a;
      }
    }
    float lt[4] = {0.f, 0.f, 0.f, 0.f};
#pragma unroll
    for (int n = 0; n < 4; ++n)
#pragma unroll
      for (int i = 0; i < 4; ++i) {
        float p = __expf(accs[n][i] - m_run[i]);
        accs[n][i] = p;
        lt[i] += p;
      }
#pragma unroll
    for (int i = 0; i < 4; ++i) {
#pragma unroll
      for (int off = 1; off < 16; off <<= 1) lt[i] += __shfl_xor(lt[i], off);
      l_run[i] += lt[i];
    }

    short* pw = Pl[wid];
#pragma unroll
    for (int n = 0; n < 4; ++n)
#pragma unroll
      for (int i = 0; i < 4; ++i)
        pw[(lh * 4 + i) * 66 + n * 16 + l15] = (short)f2bf(accs[n][i]);

    bf16x8 pa0 = *(const bf16x8*)&pw[l15 * 66 + lh * 8];
    bf16x8 pa1 = *(const bf16x8*)&pw[l15 * 66 + 32 + lh * 8];
    __builtin_amdgcn_s_setprio(1);
#pragma unroll
    for (int n = 0; n < 4; ++n) {
      const int row = n * 16 + l15;
      const int sw = row & 7;
      const int ro = row * 64;
      bf16x8 bv0 = *(const bf16x8*)&VsB[ro + ((lh ^ sw) << 3)];
      bf16x8 bv1 = *(const bf16x8*)&VsB[ro + (((4 + lh) ^ sw) << 3)];
      acc_o[n] = __builtin_amdgcn_mfma_f32_16x16x32_bf16(pa0, bv0, acc_o[n], 0, 0, 0);
      acc_o[n] = __builtin_amdgcn_mfma_f32_16x16x32_bf16(pa1, bv1, acc_o[n], 0, 0, 0);
    }
    __builtin_amdgcn_s_setprio(0);
  }

  const int b = bh >> 4, h = bh & 15;
#pragma unroll
  for (int n = 0; n < 4; ++n)
#pragma unroll
    for (int i = 0; i < 4; ++i) {
      const int r = q0 + wid * 16 + lh * 4 + i;
      const int dim = n * 16 + l15;
      float v = acc_o[n][i] / l_run[i];
      o[((size_t)(b * S + r)) * 1024 + h * 64 + dim] = f2bf(v);
    }
}

// ---------------- launch ----------------

extern "C" void kernel_launch(void* const* d_in, const int* in_sizes, int n_in,
                              void* d_out, int out_size, void* d_ws,
                              size_t ws_size, hipStream_t stream) {
  const float* x = (const float*)d_in[0];
  const float* in_project = (const float*)d_in[1];
  const float* out_project = (const float*)d_in[2];
  const float* ln1_g = (const float*)d_in[3];
  const float* ln1_b = (const float*)d_in[4];
  const float* w_up = (const float*)d_in[5];
  const float* b_up = (const float*)d_in[6];
  const float* w_down = (const float*)d_in[7];
  const float* b_down = (const float*)d_in[8];
  const float* ln2_g = (const float*)d_in[9];
  const float* ln2_b = (const float*)d_in[10];

  const int B = in_sizes[0] / (1024 * 1024);
  const int S = 1024, H = 16;
  const int M = B * S;  // 4096

  char* ws = (char*)d_ws;
  short* h_hi = (short*)(ws + 0);                 // 8MB
  short* h_lo = (short*)(ws + 8388608);           // 8MB
  float* x2 = (float*)(ws + 0);                   // 16MB, reuses h (dead)
  short* qhi = (short*)(ws + 16777216);           // 8MB
  short* qlo = (short*)(ws + 25165824);           // 8MB
  short* khi = (short*)(ws + 33554432);           // 8MB
  short* klo = (short*)(ws + 41943040);           // 8MB
  short* vt  = (short*)(ws + 50331648);           // 8MB
  short* o = (short*)(ws + 67108864);             // 8MB
  short* h2 = (short*)(ws + 75497472);            // 8MB
  short* u = (short*)(ws + 83886080);             // 16MB
  short* Wq_hi = (short*)(ws + 100663296);        // 6MB
  short* Wq_lo = (short*)(ws + 106954752);        // 6MB
  short* WoT = (short*)(ws + 113246208);          // 2MB
  short* WupT = (short*)(ws + 115343360);         // 4MB
  short* WdnT = (short*)(ws + 119537664);         // 4MB

  cast_split_kernel<<<2048, 256, 0, stream>>>(in_project, (unsigned short*)Wq_hi,
                                              (unsigned short*)Wq_lo, 3072 * 1024);
  transpose3_kernel<<<dim3(64, 64, 3), dim3(32, 8), 0, stream>>>(
      out_project, w_up, w_down, (unsigned short*)WoT, (unsigned short*)WupT,
      (unsigned short*)WdnT);

  ln_kernel<true><<<M, 256, 0, stream>>>(x, ln1_g, ln1_b, (unsigned short*)h_hi,
                                         (unsigned short*)h_lo);

  // QK GEMM (split x3, N=2048) -> q/k split bf16
  gemm_kernel<true, false, false, false, false, 1>
      <<<dim3(2048 / 128, M / 128), 256, 0, stream>>>(
          h_hi, h_lo, Wq_hi, Wq_lo, nullptr, nullptr, nullptr, M, 2048, 1024,
          (unsigned short*)qhi, (unsigned short*)qlo, (unsigned short*)khi,
          (unsigned short*)klo, nullptr);

  // V GEMM (plain, N=1024) -> v^T bf16
  gemm_kernel<false, false, false, false, false, 2>
      <<<dim3(1024 / 128, M / 128), 256, 0, stream>>>(
          h_hi, nullptr, Wq_hi + (size_t)2048 * 1024, nullptr, nullptr, nullptr,
          nullptr, M, 1024, 1024, nullptr, nullptr, nullptr, nullptr,
          (unsigned short*)vt);

  attn_mfma_kernel<<<512, 512, 0, stream>>>(
      qhi, qlo, khi, klo, vt, (unsigned short*)o, S, H);

  gemm_kernel<false, false, true, false, false, 0>
      <<<dim3(1024 / 128, M / 128), 256, 0, stream>>>(
          o, nullptr, WoT, nullptr, nullptr, x, x2, M, 1024, 1024,
          nullptr, nullptr, nullptr, nullptr, nullptr);

  ln_kernel<false><<<M, 256, 0, stream>>>(x2, ln2_g, ln2_b,
                                          (unsigned short*)h2, nullptr);

  gemm_kernel<false, true, false, true, true, 0>
      <<<dim3(2048 / 128, M / 128), 256, 0, stream>>>(
          h2, nullptr, WupT, nullptr, b_up, nullptr, u, M, 2048, 1024,
          nullptr, nullptr, nullptr, nullptr, nullptr);

  gemm_kernel<false, true, true, false, false, 0>
      <<<dim3(1024 / 128, M / 128), 256, 0, stream>>>(
          u, nullptr, WdnT, nullptr, b_down, x2, d_out, M, 1024, 2048,
          nullptr, nullptr, nullptr, nullptr, nullptr);
}

// Round 5
// 256.393 us; speedup vs baseline: 7.0505x; 1.0730x over previous
//
#include <hip/hip_runtime.h>
#include <hip/hip_bf16.h>

// ---------------------------------------------------------------------------
// ResidualAttentionBlock: LN1 -> QKV -> MHA -> out-proj(+x) -> LN2 -> FFN(+x)
// B=4, S=1024, d=1024, H=16, dh=64.
//   - GEMMs: MFMA bf16, 128x128 tile, BK=32, global_load_lds, 2-phase LDS dbuf.
//   - QK GEMM (N=2048): split-bf16 (hi+lo) x3 MFMA -> Q(x0.125),K split bf16.
//   - V GEMM (N=1024): plain bf16 -> V transposed [b,h,dim,key].
//   - Attention: MFMA flash, QBLK=128 (8 waves), XCD-aware grid (20MB fetch).
//     SWAPPED QK^T (mfma(K,Q)) -> score rows lane-local: softmax needs only
//     2 shuffles/tile (was 16); l_run kept as per-lane partial, summed once.
// ---------------------------------------------------------------------------

typedef short bf16x8 __attribute__((ext_vector_type(8)));
typedef float f32x4 __attribute__((ext_vector_type(4)));

__device__ __forceinline__ unsigned short f2bf(float f) {
  unsigned int u = __float_as_uint(f);
  unsigned int r = (u + 0x7fffu + ((u >> 16) & 1u)) >> 16;
  return (unsigned short)r;
}
__device__ __forceinline__ float bf2f(unsigned short h) {
  return __uint_as_float(((unsigned int)h) << 16);
}

__device__ __forceinline__ void gld16(const void* g, void* l) {
  __builtin_amdgcn_global_load_lds(
      (const __attribute__((address_space(1))) unsigned int*)g,
      (__attribute__((address_space(3))) unsigned int*)l, 16, 0, 0);
}

// ---------------- weight prep ----------------

__global__ void cast_split_kernel(const float* __restrict__ in,
                                  unsigned short* __restrict__ hi,
                                  unsigned short* __restrict__ lo, int n) {
  int i = blockIdx.x * blockDim.x + threadIdx.x;
  int stride = gridDim.x * blockDim.x;
  for (; i < n; i += stride) {
    float v = in[i];
    unsigned short h = f2bf(v);
    hi[i] = h;
    lo[i] = f2bf(v - bf2f(h));
  }
}

// three transposes in one launch (z selects matrix)
__global__ void transpose3_kernel(const float* __restrict__ op,
                                  const float* __restrict__ wu,
                                  const float* __restrict__ wd,
                                  unsigned short* __restrict__ oT,
                                  unsigned short* __restrict__ uT,
                                  unsigned short* __restrict__ dT) {
  const float* in;
  unsigned short* out;
  int R, C;
  if (blockIdx.z == 0) { in = op; out = oT; R = 1024; C = 1024; }
  else if (blockIdx.z == 1) { in = wu; out = uT; R = 1024; C = 2048; }
  else { in = wd; out = dT; R = 2048; C = 1024; }
  int bc = blockIdx.x << 5;
  int br = blockIdx.y << 5;
  if (bc >= C || br >= R) return;
  __shared__ float t[32][33];
  int tx = threadIdx.x, ty = threadIdx.y;
#pragma unroll
  for (int i = ty; i < 32; i += 8)
    t[i][tx] = in[(size_t)(br + i) * C + bc + tx];
  __syncthreads();
#pragma unroll
  for (int i = ty; i < 32; i += 8)
    out[(size_t)(bc + i) * R + br + tx] = f2bf(t[tx][i]);
}

// ---------------- layernorm (d=1024 fixed) ----------------

template <bool SPLIT>
__global__ __launch_bounds__(256) void ln_kernel(
    const float* __restrict__ x, const float* __restrict__ gamma,
    const float* __restrict__ beta, unsigned short* __restrict__ hi,
    unsigned short* __restrict__ lo) {
  int row = blockIdx.x, tid = threadIdx.x;
  float4 v = ((const float4*)x)[(size_t)row * 256 + tid];
  float s = v.x + v.y + v.z + v.w;
  float ss = v.x * v.x + v.y * v.y + v.z * v.z + v.w * v.w;
#pragma unroll
  for (int off = 32; off; off >>= 1) {
    s += __shfl_xor(s, off);
    ss += __shfl_xor(ss, off);
  }
  __shared__ float red[8];
  int wid = tid >> 6, lane = tid & 63;
  if (lane == 0) { red[wid] = s; red[4 + wid] = ss; }
  __syncthreads();
  s = red[0] + red[1] + red[2] + red[3];
  ss = red[4] + red[5] + red[6] + red[7];
  float mean = s * (1.f / 1024.f);
  float var = ss * (1.f / 1024.f) - mean * mean;
  float inv = rsqrtf(var + 1e-5f);
  float4 g = ((const float4*)gamma)[tid];
  float4 bt = ((const float4*)beta)[tid];
  float y[4];
  y[0] = (v.x - mean) * inv * g.x + bt.x;
  y[1] = (v.y - mean) * inv * g.y + bt.y;
  y[2] = (v.z - mean) * inv * g.z + bt.z;
  y[3] = (v.w - mean) * inv * g.w + bt.w;
  size_t o = (size_t)row * 1024 + tid * 4;
#pragma unroll
  for (int j = 0; j < 4; ++j) {
    unsigned short hb = f2bf(y[j]);
    hi[o + j] = hb;
    if (SPLIT) lo[o + j] = f2bf(y[j] - bf2f(hb));
  }
}

// ---------------- GEMM: C[M,N] = A[M,K] * W[N,K]^T ----------------
// bf16 MFMA 16x16x32, tile 128x128, BK=32, 4 waves, 2-phase LDS dbuf.
// OUTMODE: 0 normal, 1 QK-split epilogue (N=2048), 2 V-transpose epilogue.

template <bool SPLIT, bool BIAS, bool RESID, bool RELU, bool OUTBF16,
          int OUTMODE>
__global__ __launch_bounds__(256) void gemm_kernel(
    const short* __restrict__ Ah, const short* __restrict__ Al,
    const short* __restrict__ Bh, const short* __restrict__ Bl,
    const float* __restrict__ bias, const float* __restrict__ resid,
    void* __restrict__ outp, int M, int N, int K,
    unsigned short* __restrict__ qh, unsigned short* __restrict__ ql,
    unsigned short* __restrict__ kh, unsigned short* __restrict__ kl,
    unsigned short* __restrict__ vtp) {
  __shared__ short As[2][128 * 32];
  __shared__ short Bs[2][128 * 32];
  __shared__ short As2[SPLIT ? 2 : 1][SPLIT ? 128 * 32 : 8];
  __shared__ short Bs2[SPLIT ? 2 : 1][SPLIT ? 128 * 32 : 8];

  const int tid = threadIdx.x;
  const int lane = tid & 63;
  const int wid = tid >> 6;
  const int wr = (wid >> 1) << 6;
  const int wc = (wid & 1) << 6;
  const int l15 = lane & 15, lh = lane >> 4;
  const int rowBase = blockIdx.y << 7;
  const int colBase = blockIdx.x << 7;

  const int sr = tid >> 2;
  const int sc = (tid & 3) << 3;
  const int soff = sr * 32 + sc;
  const short* Ag = Ah + (size_t)(rowBase + sr) * K + sc;
  const short* Bg = Bh + (size_t)(colBase + sr) * K + sc;
  const short* Ag2 = SPLIT ? Al + (size_t)(rowBase + sr) * K + sc : nullptr;
  const short* Bg2 = SPLIT ? Bl + (size_t)(colBase + sr) * K + sc : nullptr;

  f32x4 acc[4][4];
#pragma unroll
  for (int m = 0; m < 4; ++m)
#pragma unroll
    for (int n = 0; n < 4; ++n) acc[m][n] = (f32x4){0.f, 0.f, 0.f, 0.f};

  const int kT = K >> 5;
  {
    gld16(Ag, &As[0][soff]);
    gld16(Ag + (size_t)64 * K, &As[0][soff + 64 * 32]);
    gld16(Bg, &Bs[0][soff]);
    gld16(Bg + (size_t)64 * K, &Bs[0][soff + 64 * 32]);
    if constexpr (SPLIT) {
      gld16(Ag2, &As2[0][soff]);
      gld16(Ag2 + (size_t)64 * K, &As2[0][soff + 64 * 32]);
      gld16(Bg2, &Bs2[0][soff]);
      gld16(Bg2 + (size_t)64 * K, &Bs2[0][soff + 64 * 32]);
    }
  }

  for (int kt = 0; kt < kT; ++kt) {
    __syncthreads();
    const int cb = kt & 1;
    if (kt + 1 < kT) {
      const int nb = cb ^ 1;
      const int k0 = (kt + 1) << 5;
      gld16(Ag + k0, &As[nb][soff]);
      gld16(Ag + k0 + (size_t)64 * K, &As[nb][soff + 64 * 32]);
      gld16(Bg + k0, &Bs[nb][soff]);
      gld16(Bg + k0 + (size_t)64 * K, &Bs[nb][soff + 64 * 32]);
      if constexpr (SPLIT) {
        gld16(Ag2 + k0, &As2[nb][soff]);
        gld16(Ag2 + k0 + (size_t)64 * K, &As2[nb][soff + 64 * 32]);
        gld16(Bg2 + k0, &Bs2[nb][soff]);
        gld16(Bg2 + k0 + (size_t)64 * K, &Bs2[nb][soff + 64 * 32]);
      }
    }

    const short* Asb = As[cb];
    const short* Bsb = Bs[cb];
    bf16x8 af[4], bfr[4];
#pragma unroll
    for (int m = 0; m < 4; ++m)
      af[m] = *(const bf16x8*)&Asb[(wr + m * 16 + l15) * 32 + lh * 8];
#pragma unroll
    for (int n = 0; n < 4; ++n)
      bfr[n] = *(const bf16x8*)&Bsb[(wc + n * 16 + l15) * 32 + lh * 8];
    if constexpr (SPLIT) {
      const short* Asb2 = As2[cb];
      const short* Bsb2 = Bs2[cb];
      bf16x8 af2[4], bfr2[4];
#pragma unroll
      for (int m = 0; m < 4; ++m)
        af2[m] = *(const bf16x8*)&Asb2[(wr + m * 16 + l15) * 32 + lh * 8];
#pragma unroll
      for (int n = 0; n < 4; ++n)
        bfr2[n] = *(const bf16x8*)&Bsb2[(wc + n * 16 + l15) * 32 + lh * 8];
#pragma unroll
      for (int m = 0; m < 4; ++m)
#pragma unroll
        for (int n = 0; n < 4; ++n) {
          acc[m][n] = __builtin_amdgcn_mfma_f32_16x16x32_bf16(af[m], bfr[n], acc[m][n], 0, 0, 0);
          acc[m][n] = __builtin_amdgcn_mfma_f32_16x16x32_bf16(af[m], bfr2[n], acc[m][n], 0, 0, 0);
          acc[m][n] = __builtin_amdgcn_mfma_f32_16x16x32_bf16(af2[m], bfr[n], acc[m][n], 0, 0, 0);
        }
    } else {
#pragma unroll
      for (int m = 0; m < 4; ++m)
#pragma unroll
        for (int n = 0; n < 4; ++n)
          acc[m][n] = __builtin_amdgcn_mfma_f32_16x16x32_bf16(af[m], bfr[n], acc[m][n], 0, 0, 0);
    }
  }

  const int prow = rowBase + wr + lh * 4;
  const int pcol = colBase + wc + l15;
#pragma unroll
  for (int m = 0; m < 4; ++m) {
#pragma unroll
    for (int n = 0; n < 4; ++n) {
      const int c = pcol + n * 16;
      float badd = 0.f;
      if constexpr (BIAS) badd = bias[c];
#pragma unroll
      for (int i = 0; i < 4; ++i) {
        const int r = prow + m * 16 + i;
        float v = acc[m][n][i] + badd;
        if constexpr (OUTMODE == 1) {
          const int part = c >> 10;
          const int cc = c & 1023;
          const int head = cc >> 6, dim = cc & 63;
          const int b = r >> 10, s = r & 1023;
          size_t idx = (((size_t)(b * 16 + head)) * 1024 + s) * 64 + dim;
          if (part == 0) {
            float y = v * 0.125f;
            unsigned short hb = f2bf(y);
            qh[idx] = hb;
            ql[idx] = f2bf(y - bf2f(hb));
          } else {
            unsigned short hb = f2bf(v);
            kh[idx] = hb;
            kl[idx] = f2bf(v - bf2f(hb));
          }
        } else if constexpr (OUTMODE == 2) {
          const int head = c >> 6, dim = c & 63;
          const int b = r >> 10, s = r & 1023;
          vtp[(((size_t)(b * 16 + head)) * 64 + dim) * 1024 + s] = f2bf(v);
        } else {
          if constexpr (RESID) v += resid[(size_t)r * N + c];
          if constexpr (RELU) v = fmaxf(v, 0.f);
          if constexpr (OUTBF16)
            ((unsigned short*)outp)[(size_t)r * N + c] = f2bf(v);
          else
            ((float*)outp)[(size_t)r * N + c] = v;
        }
      }
    }
  }
}

// ---------------- attention: MFMA flash, swapped QK^T ----------------
// 1D grid of 512 blocks, 512 threads (8 waves x 16 q-rows).
// XCD decode: blk&7 = xcd slot, each xcd owns 8 heads -> K/V L2-resident.
// Swapped scores: accs[n] = mfma(K_frag, Q_frag) -> accs[n][i] =
//   score[key = n*16 + lh*4 + i][query = l15]: per lane 16 scores of ONE
//   query -> softmax = local reduce + 2 shfl_xor (16,32). l_run is a per-lane
//   partial (this lane's lh key-slice), cross-lane summed once at the end.
// P written transposed to LDS [q][key] (packed b32), PV reads unchanged.

__global__ __launch_bounds__(512, 2) void attn_mfma_kernel(
    const short* __restrict__ qhi, const short* __restrict__ qlo,
    const short* __restrict__ khi, const short* __restrict__ klo,
    const short* __restrict__ vt, unsigned short* __restrict__ o,
    int S, int H) {
  __shared__ short Kh[2][64 * 64];
  __shared__ short Kl[2][64 * 64];
  __shared__ short Vs[2][64 * 64];
  __shared__ short Pl[8][16 * 66];

  const int tid = threadIdx.x, lane = tid & 63, wid = tid >> 6;
  const int l15 = lane & 15, lh = lane >> 4;
  const int blk = blockIdx.x;
  const int j = blk >> 3;
  const int bh = ((blk & 7) << 3) + (j & 7);
  const int q0 = (j >> 3) << 7;
  const size_t hb = (size_t)bh * S * 64;

  const size_t qrow = hb + (size_t)(q0 + wid * 16 + l15) * 64;
  bf16x8 aqh[2], aql[2];
  aqh[0] = *(const bf16x8*)(qhi + qrow + lh * 8);
  aqh[1] = *(const bf16x8*)(qhi + qrow + 32 + lh * 8);
  aql[0] = *(const bf16x8*)(qlo + qrow + lh * 8);
  aql[1] = *(const bf16x8*)(qlo + qrow + 32 + lh * 8);

  // softmax state: per-lane, query = l15; l_run is partial (this lh slice)
  float m_run = -INFINITY, l_run = 0.f;
  // PV accumulator: query = lh*4+i, dim = n*16+l15
  f32x4 acc_o[4];
#pragma unroll
  for (int n = 0; n < 4; ++n) acc_o[n] = (f32x4){0.f, 0.f, 0.f, 0.f};

  const int r0 = tid >> 3, c0 = tid & 7;
  const int sw0 = ((c0 ^ (r0 & 7)) << 3);

  const int nT = S >> 6;
  {
    gld16(khi + hb + r0 * 64 + sw0, (char*)Kh[0] + tid * 16);
    gld16(klo + hb + r0 * 64 + sw0, (char*)Kl[0] + tid * 16);
    gld16(vt + hb + (size_t)r0 * S + sw0, (char*)Vs[0] + tid * 16);
  }

  for (int kt = 0; kt < nT; ++kt) {
    __syncthreads();
    const int cb = kt & 1;
    if (kt + 1 < nT) {
      const int nb = cb ^ 1;
      const size_t kb = hb + (size_t)(kt + 1) * 64 * 64;
      gld16(khi + kb + r0 * 64 + sw0, (char*)Kh[nb] + tid * 16);
      gld16(klo + kb + r0 * 64 + sw0, (char*)Kl[nb] + tid * 16);
      const short* vg = vt + hb + (size_t)(kt + 1) * 64;
      gld16(vg + (size_t)r0 * S + sw0, (char*)Vs[nb] + tid * 16);
    }

    const short* KhB = Kh[cb];
    const short* KlB = Kl[cb];
    const short* VsB = Vs[cb];

    // swapped scores: accs[n][i] = score[key=n*16+lh*4+i][query=l15]
    f32x4 accs[4];
#pragma unroll
    for (int n = 0; n < 4; ++n) accs[n] = (f32x4){0.f, 0.f, 0.f, 0.f};
    __builtin_amdgcn_s_setprio(1);
#pragma unroll
    for (int n = 0; n < 4; ++n) {
      const int row = n * 16 + l15;
      const int sw = row & 7;
      const int ro = row * 64;
      bf16x8 bh0 = *(const bf16x8*)&KhB[ro + ((lh ^ sw) << 3)];
      bf16x8 bh1 = *(const bf16x8*)&KhB[ro + (((4 + lh) ^ sw) << 3)];
      bf16x8 bl0 = *(const bf16x8*)&KlB[ro + ((lh ^ sw) << 3)];
      bf16x8 bl1 = *(const bf16x8*)&KlB[ro + (((4 + lh) ^ sw) << 3)];
      accs[n] = __builtin_amdgcn_mfma_f32_16x16x32_bf16(bh0, aqh[0], accs[n], 0, 0, 0);
      accs[n] = __builtin_amdgcn_mfma_f32_16x16x32_bf16(bh1, aqh[1], accs[n], 0, 0, 0);
      accs[n] = __builtin_amdgcn_mfma_f32_16x16x32_bf16(bl0, aqh[0], accs[n], 0, 0, 0);
      accs[n] = __builtin_amdgcn_mfma_f32_16x16x32_bf16(bl1, aqh[1], accs[n], 0, 0, 0);
      accs[n] = __builtin_amdgcn_mfma_f32_16x16x32_bf16(bh0, aql[0], accs[n], 0, 0, 0);
      accs[n] = __builtin_amdgcn_mfma_f32_16x16x32_bf16(bh1, aql[1], accs[n], 0, 0, 0);
    }
    __builtin_amdgcn_s_setprio(0);

    // local tile-max over this lane's 16 scores, then 2 shfls across lh
    float m01 = fmaxf(fmaxf(accs[0][0], accs[0][1]), fmaxf(accs[0][2], accs[0][3]));
    float m11 = fmaxf(fmaxf(accs[1][0], accs[1][1]), fmaxf(accs[1][2], accs[1][3]));
    float m21 = fmaxf(fmaxf(accs[2][0], accs[2][1]), fmaxf(accs[2][2], accs[2][3]));
    float m31 = fmaxf(fmaxf(accs[3][0], accs[3][1]), fmaxf(accs[3][2], accs[3][3]));
    float mt = fmaxf(fmaxf(m01, m11), fmaxf(m21, m31));
    mt = fmaxf(mt, __shfl_xor(mt, 16));
    mt = fmaxf(mt, __shfl_xor(mt, 32));  // query-uniform across lh groups

    // defer-max (THR=8)
    if (__any(mt > m_run + 8.f)) {
      float mn = fmaxf(m_run, mt);
      float a = __expf(m_run - mn);
      m_run = mn;
      l_run *= a;
      // broadcast alpha into acc_o's query domain (q = lh*4+i)
      float a0 = __shfl(a, lh * 4 + 0);
      float a1 = __shfl(a, lh * 4 + 1);
      float a2 = __shfl(a, lh * 4 + 2);
      float a3 = __shfl(a, lh * 4 + 3);
#pragma unroll
      for (int n = 0; n < 4; ++n) {
        acc_o[n][0] *= a0; acc_o[n][1] *= a1;
        acc_o[n][2] *= a2; acc_o[n][3] *= a3;
      }
    }

    // p = exp(s - m); accumulate partial l; pack P -> LDS [q][key]
    short* pw = Pl[wid];
    unsigned int* pw32 = (unsigned int*)pw;
#pragma unroll
    for (int n = 0; n < 4; ++n) {
      float p0 = __expf(accs[n][0] - m_run);
      float p1 = __expf(accs[n][1] - m_run);
      float p2 = __expf(accs[n][2] - m_run);
      float p3 = __expf(accs[n][3] - m_run);
      l_run += (p0 + p1) + (p2 + p3);
      // short addr = l15*66 + n*16 + lh*4 + i  (row stride 66 -> 33 dwords)
      pw32[l15 * 33 + n * 8 + lh * 2 + 0] =
          ((unsigned int)f2bf(p1) << 16) | f2bf(p0);
      pw32[l15 * 33 + n * 8 + lh * 2 + 1] =
          ((unsigned int)f2bf(p3) << 16) | f2bf(p2);
    }

    bf16x8 pa0 = *(const bf16x8*)&pw[l15 * 66 + lh * 8];
    bf16x8 pa1 = *(const bf16x8*)&pw[l15 * 66 + 32 + lh * 8];
    __builtin_amdgcn_s_setprio(1);
#pragma unroll
    for (int n = 0; n < 4; ++n) {
      const int row = n * 16 + l15;
      const int sw = row & 7;
      const int ro = row * 64;
      bf16x8 bv0 = *(const bf16x8*)&VsB[ro + ((lh ^ sw) << 3)];
      bf16x8 bv1 = *(const bf16x8*)&VsB[ro + (((4 + lh) ^ sw) << 3)];
      acc_o[n] = __builtin_amdgcn_mfma_f32_16x16x32_bf16(pa0, bv0, acc_o[n], 0, 0, 0);
      acc_o[n] = __builtin_amdgcn_mfma_f32_16x16x32_bf16(pa1, bv1, acc_o[n], 0, 0, 0);
    }
    __builtin_amdgcn_s_setprio(0);
  }

  // total l per query: sum partials across lh groups, then reciprocal,
  // then gather into acc_o's query domain (q = lh*4+i)
  float lsum = l_run + __shfl_xor(l_run, 16);
  lsum += __shfl_xor(lsum, 32);
  float lrec = 1.0f / lsum;
  float r0i = __shfl(lrec, lh * 4 + 0);
  float r1i = __shfl(lrec, lh * 4 + 1);
  float r2i = __shfl(lrec, lh * 4 + 2);
  float r3i = __shfl(lrec, lh * 4 + 3);

  const int b = bh >> 4, h = bh & 15;
#pragma unroll
  for (int n = 0; n < 4; ++n) {
    const int dim = n * 16 + l15;
    const float rs[4] = {r0i, r1i, r2i, r3i};
#pragma unroll
    for (int i = 0; i < 4; ++i) {
      const int r = q0 + wid * 16 + lh * 4 + i;
      o[((size_t)(b * S + r)) * 1024 + h * 64 + dim] = f2bf(acc_o[n][i] * rs[i]);
    }
  }
}

// ---------------- launch ----------------

extern "C" void kernel_launch(void* const* d_in, const int* in_sizes, int n_in,
                              void* d_out, int out_size, void* d_ws,
                              size_t ws_size, hipStream_t stream) {
  const float* x = (const float*)d_in[0];
  const float* in_project = (const float*)d_in[1];
  const float* out_project = (const float*)d_in[2];
  const float* ln1_g = (const float*)d_in[3];
  const float* ln1_b = (const float*)d_in[4];
  const float* w_up = (const float*)d_in[5];
  const float* b_up = (const float*)d_in[6];
  const float* w_down = (const float*)d_in[7];
  const float* b_down = (const float*)d_in[8];
  const float* ln2_g = (const float*)d_in[9];
  const float* ln2_b = (const float*)d_in[10];

  const int B = in_sizes[0] / (1024 * 1024);
  const int S = 1024, H = 16;
  const int M = B * S;  // 4096

  char* ws = (char*)d_ws;
  short* h_hi = (short*)(ws + 0);                 // 8MB
  short* h_lo = (short*)(ws + 8388608);           // 8MB
  float* x2 = (float*)(ws + 0);                   // 16MB, reuses h (dead)
  short* qhi = (short*)(ws + 16777216);           // 8MB
  short* qlo = (short*)(ws + 25165824);           // 8MB
  short* khi = (short*)(ws + 33554432);           // 8MB
  short* klo = (short*)(ws + 41943040);           // 8MB
  short* vt  = (short*)(ws + 50331648);           // 8MB
  short* o = (short*)(ws + 67108864);             // 8MB
  short* h2 = (short*)(ws + 75497472);            // 8MB
  short* u = (short*)(ws + 83886080);             // 16MB
  short* Wq_hi = (short*)(ws + 100663296);        // 6MB
  short* Wq_lo = (short*)(ws + 106954752);        // 6MB
  short* WoT = (short*)(ws + 113246208);          // 2MB
  short* WupT = (short*)(ws + 115343360);         // 4MB
  short* WdnT = (short*)(ws + 119537664);         // 4MB

  cast_split_kernel<<<2048, 256, 0, stream>>>(in_project, (unsigned short*)Wq_hi,
                                              (unsigned short*)Wq_lo, 3072 * 1024);
  transpose3_kernel<<<dim3(64, 64, 3), dim3(32, 8), 0, stream>>>(
      out_project, w_up, w_down, (unsigned short*)WoT, (unsigned short*)WupT,
      (unsigned short*)WdnT);

  ln_kernel<true><<<M, 256, 0, stream>>>(x, ln1_g, ln1_b, (unsigned short*)h_hi,
                                         (unsigned short*)h_lo);

  // QK GEMM (split x3, N=2048) -> q/k split bf16
  gemm_kernel<true, false, false, false, false, 1>
      <<<dim3(2048 / 128, M / 128), 256, 0, stream>>>(
          h_hi, h_lo, Wq_hi, Wq_lo, nullptr, nullptr, nullptr, M, 2048, 1024,
          (unsigned short*)qhi, (unsigned short*)qlo, (unsigned short*)khi,
          (unsigned short*)klo, nullptr);

  // V GEMM (plain, N=1024) -> v^T bf16
  gemm_kernel<false, false, false, false, false, 2>
      <<<dim3(1024 / 128, M / 128), 256, 0, stream>>>(
          h_hi, nullptr, Wq_hi + (size_t)2048 * 1024, nullptr, nullptr, nullptr,
          nullptr, M, 1024, 1024, nullptr, nullptr, nullptr, nullptr,
          (unsigned short*)vt);

  attn_mfma_kernel<<<512, 512, 0, stream>>>(
      qhi, qlo, khi, klo, vt, (unsigned short*)o, S, H);

  gemm_kernel<false, false, true, false, false, 0>
      <<<dim3(1024 / 128, M / 128), 256, 0, stream>>>(
          o, nullptr, WoT, nullptr, nullptr, x, x2, M, 1024, 1024,
          nullptr, nullptr, nullptr, nullptr, nullptr);

  ln_kernel<false><<<M, 256, 0, stream>>>(x2, ln2_g, ln2_b,
                                          (unsigned short*)h2, nullptr);

  gemm_kernel<false, true, false, true, true, 0>
      <<<dim3(2048 / 128, M / 128), 256, 0, stream>>>(
          h2, nullptr, WupT, nullptr, b_up, nullptr, u, M, 2048, 1024,
          nullptr, nullptr, nullptr, nullptr, nullptr);

  gemm_kernel<false, true, true, false, false, 0>
      <<<dim3(1024 / 128, M / 128), 256, 0, stream>>>(
          u, nullptr, WdnT, nullptr, b_down, x2, d_out, M, 1024, 2048,
          nullptr, nullptr, nullptr, nullptr, nullptr);
}